// Round 1
// baseline (3337.626 us; speedup 1.0000x reference)
//
#include <hip/hip_runtime.h>
#include <math.h>

// Problem constants (fixed by setup_inputs)
#define Bz 8
#define Tz 1024
#define Dz 512
#define FFz 2048
#define Hz 8
#define DHz 64
#define Mz (Bz * Tz)  // 8192 rows

// ---------------------------------------------------------------------------
// zero fill (colsum accumulators must start at 0; ws is poisoned 0xAA)
// ---------------------------------------------------------------------------
__global__ __launch_bounds__(256) void zero_kernel(float* __restrict__ p, int n) {
  int i = blockIdx.x * 256 + threadIdx.x;
  if (i < n) p[i] = 0.f;
}

// ---------------------------------------------------------------------------
// fp32 GEMM: C[M,N] = A[M,K] @ B[K,N], all row-major, optional fused ReLU.
// 128x128 tile, BK=16, 256 threads, 8x8 micro-tile per thread.
// LDS strides padded to 132 floats (odd multiple of 4) -> <=2-way bank alias.
// ---------------------------------------------------------------------------
__global__ __launch_bounds__(256) void gemm_kernel(
    const float* __restrict__ A, const float* __restrict__ Bm,
    float* __restrict__ C, int M, int N, int K, int relu)
{
  __shared__ float As[16][132];  // [k][m]
  __shared__ float Bs[16][132];  // [k][n]
  const int tid = threadIdx.x;
  const int bm = blockIdx.y * 128;
  const int bn = blockIdx.x * 128;
  const int tx = tid & 15, ty = tid >> 4;
  float acc[8][8];
#pragma unroll
  for (int i = 0; i < 8; ++i)
#pragma unroll
    for (int j = 0; j < 8; ++j) acc[i][j] = 0.f;

  for (int k0 = 0; k0 < K; k0 += 16) {
#pragma unroll
    for (int i = 0; i < 2; ++i) {
      int idx = tid + i * 256;
      int r = idx >> 2, kv = (idx & 3) << 2;
      float4 a = *reinterpret_cast<const float4*>(&A[(size_t)(bm + r) * K + k0 + kv]);
      As[kv + 0][r] = a.x; As[kv + 1][r] = a.y; As[kv + 2][r] = a.z; As[kv + 3][r] = a.w;
      int kk = idx >> 5, nv = (idx & 31) << 2;
      *reinterpret_cast<float4*>(&Bs[kk][nv]) =
          *reinterpret_cast<const float4*>(&Bm[(size_t)(k0 + kk) * N + bn + nv]);
    }
    __syncthreads();
#pragma unroll
    for (int kk = 0; kk < 16; ++kk) {
      float ar[8], br[8];
#pragma unroll
      for (int i = 0; i < 8; ++i) ar[i] = As[kk][ty * 8 + i];
#pragma unroll
      for (int j = 0; j < 4; ++j) {
        br[j]     = Bs[kk][tx * 4 + j];       // cols tx*4..+3
        br[4 + j] = Bs[kk][64 + tx * 4 + j];  // cols 64+tx*4..+3 (split avoids 4-way bank conflict)
      }
#pragma unroll
      for (int i = 0; i < 8; ++i)
#pragma unroll
        for (int j = 0; j < 8; ++j) acc[i][j] += ar[i] * br[j];
    }
    __syncthreads();
  }
#pragma unroll
  for (int i = 0; i < 8; ++i) {
    size_t row = (size_t)(bm + ty * 8 + i);
    float4 v0, v1;
    v0.x = acc[i][0]; v0.y = acc[i][1]; v0.z = acc[i][2]; v0.w = acc[i][3];
    v1.x = acc[i][4]; v1.y = acc[i][5]; v1.z = acc[i][6]; v1.w = acc[i][7];
    if (relu) {
      v0.x = fmaxf(v0.x, 0.f); v0.y = fmaxf(v0.y, 0.f); v0.z = fmaxf(v0.z, 0.f); v0.w = fmaxf(v0.w, 0.f);
      v1.x = fmaxf(v1.x, 0.f); v1.y = fmaxf(v1.y, 0.f); v1.z = fmaxf(v1.z, 0.f); v1.w = fmaxf(v1.w, 0.f);
    }
    *reinterpret_cast<float4*>(&C[row * N + bn + tx * 4]) = v0;
    *reinterpret_cast<float4*>(&C[row * N + bn + 64 + tx * 4]) = v1;
  }
}

// ---------------------------------------------------------------------------
// Fused attention for one (b, h, 16-query tile): online softmax with scores
// held in registers across both passes (K staged once, scores computed once).
// Q/K/V layout: (B, T, H*dh) row-major (direct GEMM output, no reshape pass).
// ctx written in the same layout. colsum[b,k] += sum_q probs / H (atomic).
// MASKED: block-diagonal window mask via ids (score -> -inf off-window).
// LDS: rows 0..15 = Q tile (pass1) / P tile (pass2); rows 16..79 = K^T / V.
// Stride 68 floats -> <=2-way bank alias on strided fragment reads.
// ---------------------------------------------------------------------------
template <bool MASKED>
__global__ __launch_bounds__(256) void attn_kernel(
    const float* __restrict__ Qf, const float* __restrict__ Kf, const float* __restrict__ Vf,
    const int* __restrict__ ids, float* __restrict__ ctx, float* __restrict__ colsum)
{
  __shared__ float lds[80][68];
  __shared__ float redm[16][16], redl[16][16];
  __shared__ float srm[16], srz[16];
  __shared__ int qid[16];
  __shared__ int kid[64];

  const int tid = threadIdx.x;
  const int nqt = Tz / 16;
  const int qt = blockIdx.x % nqt;
  const int h  = (blockIdx.x / nqt) % Hz;
  const int b  = blockIdx.x / (nqt * Hz);
  const int q0 = qt * 16;
  const int row = tid & 15, cg = tid >> 4;  // thread -> (q-row, 4-col group)

  {  // load Q tile 16x64: one float4 per thread
    int r = tid >> 4, dv = (tid & 15) << 2;
    *reinterpret_cast<float4*>(&lds[r][dv]) = *reinterpret_cast<const float4*>(
        &Qf[((size_t)(b * Tz + q0 + r)) * Dz + h * DHz + dv]);
  }
  if (MASKED && tid < 16) qid[tid] = ids[b * Tz + q0 + tid];

  float sreg[16][4];  // scores for this thread's 4 columns, all 16 key tiles
  float m = -INFINITY, l = 0.f;

#pragma unroll
  for (int t = 0; t < 16; ++t) {
    __syncthreads();
    const int k0 = t * 64;
#pragma unroll
    for (int i = 0; i < 4; ++i) {  // stage K tile transposed: Kt[d][key]
      int idx = tid + i * 256;
      int r = idx >> 4, dv = (idx & 15) << 2;
      float4 kv4 = *reinterpret_cast<const float4*>(
          &Kf[((size_t)(b * Tz + k0 + r)) * Dz + h * DHz + dv]);
      lds[16 + dv + 0][r] = kv4.x;
      lds[16 + dv + 1][r] = kv4.y;
      lds[16 + dv + 2][r] = kv4.z;
      lds[16 + dv + 3][r] = kv4.w;
    }
    if (MASKED && tid < 64) kid[tid] = ids[b * Tz + k0 + tid];
    __syncthreads();
    float s0 = 0.f, s1 = 0.f, s2 = 0.f, s3 = 0.f;
#pragma unroll 4
    for (int d = 0; d < 64; ++d) {
      float qd = lds[row][d];                                             // broadcast-ish, 2-way
      float4 kt = *reinterpret_cast<const float4*>(&lds[16 + d][cg * 4]); // 2-way
      s0 += qd * kt.x; s1 += qd * kt.y; s2 += qd * kt.z; s3 += qd * kt.w;
    }
    float sv[4] = {s0 * 0.125f, s1 * 0.125f, s2 * 0.125f, s3 * 0.125f};  // 1/sqrt(64)
#pragma unroll
    for (int j = 0; j < 4; ++j) {
      bool ok = true;
      if (MASKED) ok = (kid[cg * 4 + j] == qid[row]);
      float s = ok ? sv[j] : -INFINITY;
      sreg[t][j] = s;
      if (ok) {  // online update; m=-inf start handled (0*expf(-inf)=0)
        float nm = fmaxf(m, s);
        l = l * __expf(m - nm) + __expf(s - nm);
        m = nm;
      }
    }
  }
  // combine per-thread (m,l) across the 16 col-groups of each row
  redm[cg][row] = m;
  redl[cg][row] = l;
  __syncthreads();
  if (tid < 16) {
    float M = -INFINITY, L = 0.f;
    for (int c = 0; c < 16; ++c) {
      float mc = redm[c][tid], lc = redl[c][tid];
      float nm = fmaxf(M, mc);
      if (nm > -INFINITY) {
        L = L * __expf(M - nm) + lc * __expf(mc - nm);
        M = nm;
      }
    }
    srm[tid] = M;
    srz[tid] = 1.f / L;  // every row has >=1 unmasked key (diagonal)
  }
  __syncthreads();
  const float mrow = srm[row], invZ = srz[row];

  float a0 = 0.f, a1 = 0.f, a2 = 0.f, a3 = 0.f;  // ctx[row][cg*4..+3]
#pragma unroll
  for (int t = 0; t < 16; ++t) {
    __syncthreads();
    const int k0 = t * 64;
#pragma unroll
    for (int i = 0; i < 4; ++i) {  // stage V tile row-major into rows 16..79
      int idx = tid + i * 256;
      int r = idx >> 4, dv = (idx & 15) << 2;
      *reinterpret_cast<float4*>(&lds[16 + r][dv]) = *reinterpret_cast<const float4*>(
          &Vf[((size_t)(b * Tz + k0 + r)) * Dz + h * DHz + dv]);
    }
    float4 p4;  // masked scores are -inf -> expf gives exact 0
    p4.x = __expf(sreg[t][0] - mrow) * invZ;
    p4.y = __expf(sreg[t][1] - mrow) * invZ;
    p4.z = __expf(sreg[t][2] - mrow) * invZ;
    p4.w = __expf(sreg[t][3] - mrow) * invZ;
    *reinterpret_cast<float4*>(&lds[row][cg * 4]) = p4;  // P tile rows 0..15
    __syncthreads();
    if (tid < 64) {  // column sums of P over the 16 queries -> attention received per key
      float cs = 0.f;
#pragma unroll
      for (int r = 0; r < 16; ++r) cs += lds[r][tid];
      atomicAdd(&colsum[b * Tz + k0 + tid], cs * (1.f / Hz));
    }
#pragma unroll 4
    for (int kk = 0; kk < 64; ++kk) {
      float p = lds[row][kk];
      float4 vv = *reinterpret_cast<const float4*>(&lds[16 + kk][cg * 4]);
      a0 += p * vv.x; a1 += p * vv.y; a2 += p * vv.z; a3 += p * vv.w;
    }
  }
  float4 o; o.x = a0; o.y = a1; o.z = a2; o.w = a3;
  *reinterpret_cast<float4*>(&ctx[((size_t)(b * Tz + q0 + row)) * Dz + h * DHz + cg * 4]) = o;
}

// ---------------------------------------------------------------------------
// out = LayerNorm(resid + delta), D=512, no affine. One 256-thread block/row.
// ---------------------------------------------------------------------------
__global__ __launch_bounds__(256) void ln_kernel(const float* __restrict__ resid,
    const float* __restrict__ delta, float* __restrict__ out)
{
  const size_t base = (size_t)blockIdx.x * Dz;
  const int tid = threadIdx.x;
  float x0 = resid[base + tid] + delta[base + tid];
  float x1 = resid[base + tid + 256] + delta[base + tid + 256];
  __shared__ float red[4];
  float s = x0 + x1;
#pragma unroll
  for (int off = 32; off; off >>= 1) s += __shfl_down(s, off);
  if ((tid & 63) == 0) red[tid >> 6] = s;
  __syncthreads();
  const float mean = (red[0] + red[1] + red[2] + red[3]) * (1.f / Dz);
  __syncthreads();
  float d0 = x0 - mean, d1 = x1 - mean;
  float v = d0 * d0 + d1 * d1;
#pragma unroll
  for (int off = 32; off; off >>= 1) v += __shfl_down(v, off);
  if ((tid & 63) == 0) red[tid >> 6] = v;
  __syncthreads();
  const float var = (red[0] + red[1] + red[2] + red[3]) * (1.f / Dz);
  const float rstd = rsqrtf(var + 1e-5f);
  out[base + tid] = d0 * rstd;
  out[base + tid + 256] = d1 * rstd;
}

// ---------------------------------------------------------------------------
// Per batch: min-max normalize colsum, threshold 0.5, run-length window scan
// (length-1 runs absorbed into the following run), emit ids / starts / count.
// ---------------------------------------------------------------------------
__global__ __launch_bounds__(256) void window_ids_kernel(const float* __restrict__ cs,
    int* __restrict__ ids, int* __restrict__ wst, int* __restrict__ nwin)
{
  const int b = blockIdx.x, tid = threadIdx.x;
  __shared__ float vals[Tz];
  __shared__ unsigned char wb[Tz];
  __shared__ int sids[Tz];
  __shared__ float rmin[4], rmax[4];
  float mn = INFINITY, mx = -INFINITY;
  for (int t = tid; t < Tz; t += 256) {
    float v = cs[b * Tz + t];
    vals[t] = v;
    mn = fminf(mn, v); mx = fmaxf(mx, v);
  }
#pragma unroll
  for (int off = 32; off; off >>= 1) {
    mn = fminf(mn, __shfl_down(mn, off));
    mx = fmaxf(mx, __shfl_down(mx, off));
  }
  if ((tid & 63) == 0) { rmin[tid >> 6] = mn; rmax[tid >> 6] = mx; }
  __syncthreads();
  mn = fminf(fminf(rmin[0], rmin[1]), fminf(rmin[2], rmin[3]));
  mx = fmaxf(fmaxf(rmax[0], rmax[1]), fmaxf(rmax[2], rmax[3]));
  const float inv = 1.f / (mx - mn + 1e-8f);
  for (int t = tid; t < Tz; t += 256) wb[t] = (((vals[t] - mn) * inv) >= 0.5f) ? 1 : 0;
  __syncthreads();
  if (tid == 0) {  // faithful sequential scan, 1023 steps
    int cur = wb[0], start = 0, wid = 0;
    sids[0] = 0;
    wst[b * (Tz + 1)] = 0;
    for (int t = 1; t < Tz; ++t) {
      int wt = wb[t];
      if (wt != cur) {
        cur = wt;
        if (start + 1 != t) {  // close (not a merge of a length-1 run)
          start = t;
          ++wid;
          wst[b * (Tz + 1) + wid] = t;
        }
      }
      sids[t] = wid;
    }
    nwin[b] = wid + 1;
    wst[b * (Tz + 1) + wid + 1] = Tz;
  }
  __syncthreads();
  for (int t = tid; t < Tz; t += 256) ids[b * Tz + t] = sids[t];
}

// ---------------------------------------------------------------------------
// wl[b,:] = softmax over keys of layer-2 colsum (already includes 1/H).
// ---------------------------------------------------------------------------
__global__ __launch_bounds__(256) void wl_softmax_kernel(const float* __restrict__ cs,
                                                         float* __restrict__ wl)
{
  const int b = blockIdx.x, tid = threadIdx.x;
  __shared__ float vals[Tz];
  __shared__ float red[4];
  float mx = -INFINITY;
  for (int t = tid; t < Tz; t += 256) {
    float v = cs[b * Tz + t];
    vals[t] = v;
    mx = fmaxf(mx, v);
  }
#pragma unroll
  for (int off = 32; off; off >>= 1) mx = fmaxf(mx, __shfl_down(mx, off));
  if ((tid & 63) == 0) red[tid >> 6] = mx;
  __syncthreads();
  mx = fmaxf(fmaxf(red[0], red[1]), fmaxf(red[2], red[3]));
  __syncthreads();
  float se = 0.f;
  for (int t = tid; t < Tz; t += 256) {
    float e = expf(vals[t] - mx);
    vals[t] = e;
    se += e;
  }
#pragma unroll
  for (int off = 32; off; off >>= 1) se += __shfl_down(se, off);
  if ((tid & 63) == 0) red[tid >> 6] = se;
  __syncthreads();
  const float inv = 1.f / (red[0] + red[1] + red[2] + red[3]);
  for (int t = tid; t < Tz; t += 256) wl[b * Tz + t] = vals[t] * inv;
}

// ---------------------------------------------------------------------------
// word_tokens rows of output 0: out0[b, w, :] = sum_{t in window w} out_l*wl.
// Windows are contiguous token ranges; rows w >= nwin are zero.
// ---------------------------------------------------------------------------
__global__ __launch_bounds__(256) void word_tokens_kernel(const float* __restrict__ outl,
    const float* __restrict__ wl, const int* __restrict__ wst, const int* __restrict__ nwin,
    float* __restrict__ out)
{
  const int w = blockIdx.x & (Tz - 1);
  const int b = blockIdx.x >> 10;
  const int tid = threadIdx.x;
  float a0 = 0.f, a1 = 0.f;
  if (w < nwin[b]) {
    const int s = wst[b * (Tz + 1) + w], e = wst[b * (Tz + 1) + w + 1];
    for (int t = s; t < e; ++t) {
      const float sc = wl[b * Tz + t];
      const float* p = &outl[((size_t)(b * Tz + t)) * Dz];
      a0 += p[tid] * sc;
      a1 += p[tid + 256] * sc;
    }
  }
  float* o = &out[((size_t)(b * 2 * Tz + w)) * Dz];
  o[tid] = a0;
  o[tid + 256] = a1;
}

// ---------------------------------------------------------------------------
// out0 rows [T, 2T): copy of the original input x.
// ---------------------------------------------------------------------------
__global__ __launch_bounds__(256) void copy_x_kernel(const float* __restrict__ x,
                                                     float* __restrict__ out)
{
  size_t i = (size_t)blockIdx.x * 256 + threadIdx.x;
  size_t idx = i * 4;
  size_t rowi = idx >> 9;        // b*T + t
  size_t d = idx & 511;
  size_t b = rowi >> 10, t = rowi & 1023;
  float4 v = *reinterpret_cast<const float4*>(&x[idx]);
  *reinterpret_cast<float4*>(&out[(((b * 2 * Tz) + Tz + t) << 9) + d]) = v;
}

// ---------------------------------------------------------------------------
// Output 1: window_mapping[b, w, j] = (ids[b,j] == w).
// ---------------------------------------------------------------------------
__global__ __launch_bounds__(256) void winmap_kernel(const int* __restrict__ ids,
                                                     float* __restrict__ out2)
{
  const int w = blockIdx.x & (Tz - 1);
  const int b = blockIdx.x >> 10;
  const int tid = threadIdx.x;
  const int j = tid * 4;
  int4 id4 = *reinterpret_cast<const int4*>(&ids[b * Tz + j]);
  float4 v;
  v.x = (id4.x == w) ? 1.f : 0.f;
  v.y = (id4.y == w) ? 1.f : 0.f;
  v.z = (id4.z == w) ? 1.f : 0.f;
  v.w = (id4.w == w) ? 1.f : 0.f;
  *reinterpret_cast<float4*>(&out2[((size_t)(b * Tz + w)) * Tz + j]) = v;
}

// ---------------------------------------------------------------------------
// Orchestration. Workspace layout (floats); peak need ~134.4 MB.
// ---------------------------------------------------------------------------
extern "C" void kernel_launch(void* const* d_in, const int* in_sizes, int n_in,
                              void* d_out, int out_size, void* d_ws, size_t ws_size,
                              hipStream_t stream)
{
  (void)in_sizes; (void)n_in; (void)out_size; (void)ws_size;
  const float* x     = (const float*)d_in[0];
  const float* vqkv  = (const float*)d_in[1];
  const float* voutw = (const float*)d_in[2];
  const float* vw1   = (const float*)d_in[3];
  const float* vw2   = (const float*)d_in[4];
  const float* lqkv  = (const float*)d_in[5];
  const float* loutw = (const float*)d_in[6];
  const float* lw1   = (const float*)d_in[7];
  const float* lw2   = (const float*)d_in[8];
  float* out = (float*)d_out;
  float* ws  = (float*)d_ws;

  // workspace layout (element offsets). HID aliases Q/K/V/CTX (dead then).
  float* Q    = ws + 0;          // 4,194,304
  float* Kb   = ws + 4194304;    // 4,194,304
  float* Vb   = ws + 8388608;    // 4,194,304
  float* CTX  = ws + 12582912;   // 4,194,304
  float* HID  = ws + 0;          // 16,777,216 (aliases Q..CTX during FFN)
  float* Y1   = ws + 16777216;   // 4,194,304
  float* PROJ = ws + 20971520;   // 4,194,304
  float* OUTV = ws + 25165824;   // 4,194,304
  float* OUTL = ws + 29360128;   // 4,194,304
  float* CS1  = ws + 33554432;   // 8192
  float* CS2  = ws + 33562624;   // 8192
  float* WL   = ws + 33570816;   // 8192
  int*   IDS  = (int*)(ws + 33579008);  // 8192
  int*   WST  = (int*)(ws + 33587200);  // 8*1025
  int*   NWIN = (int*)(ws + 33595400);  // 8

  dim3 blk(256);
  zero_kernel<<<dim3(64), blk, 0, stream>>>(CS1, 16384);  // CS1+CS2 contiguous

  auto gemm = [&](const float* A, const float* Bm, float* C, int M, int N, int K, int relu) {
    gemm_kernel<<<dim3(N / 128, M / 128), blk, 0, stream>>>(A, Bm, C, M, N, K, relu);
  };

  // ---------------- layer 1 (vanilla) ----------------
  gemm(x, vqkv + 0 * Dz * Dz, Q,  Mz, Dz, Dz, 0);
  gemm(x, vqkv + 1 * Dz * Dz, Kb, Mz, Dz, Dz, 0);
  gemm(x, vqkv + 2 * Dz * Dz, Vb, Mz, Dz, Dz, 0);
  attn_kernel<false><<<dim3(Bz * Hz * (Tz / 16)), blk, 0, stream>>>(Q, Kb, Vb, nullptr, CTX, CS1);
  gemm(CTX, voutw, PROJ, Mz, Dz, Dz, 0);
  ln_kernel<<<dim3(Mz), blk, 0, stream>>>(x, PROJ, Y1);
  gemm(Y1, vw1, HID, Mz, FFz, Dz, 1);
  gemm(HID, vw2, PROJ, Mz, Dz, FFz, 0);
  ln_kernel<<<dim3(Mz), blk, 0, stream>>>(Y1, PROJ, OUTV);

  // ---------------- dynamic window generation ----------------
  window_ids_kernel<<<dim3(Bz), blk, 0, stream>>>(CS1, IDS, WST, NWIN);

  // ---------------- layer 2 (block-diagonal window mask) ----------------
  gemm(OUTV, lqkv + 0 * Dz * Dz, Q,  Mz, Dz, Dz, 0);
  gemm(OUTV, lqkv + 1 * Dz * Dz, Kb, Mz, Dz, Dz, 0);
  gemm(OUTV, lqkv + 2 * Dz * Dz, Vb, Mz, Dz, Dz, 0);
  attn_kernel<true><<<dim3(Bz * Hz * (Tz / 16)), blk, 0, stream>>>(Q, Kb, Vb, IDS, CTX, CS2);
  gemm(CTX, loutw, PROJ, Mz, Dz, Dz, 0);
  ln_kernel<<<dim3(Mz), blk, 0, stream>>>(OUTV, PROJ, Y1);
  gemm(Y1, lw1, HID, Mz, FFz, Dz, 1);
  gemm(HID, lw2, PROJ, Mz, Dz, FFz, 0);
  ln_kernel<<<dim3(Mz), blk, 0, stream>>>(Y1, PROJ, OUTL);

  // ---------------- pooling + outputs ----------------
  wl_softmax_kernel<<<dim3(Bz), blk, 0, stream>>>(CS2, WL);
  word_tokens_kernel<<<dim3(Bz * Tz), blk, 0, stream>>>(OUTL, WL, WST, NWIN, out);
  copy_x_kernel<<<dim3(Bz * Tz * Dz / 1024), blk, 0, stream>>>(x, out);
  winmap_kernel<<<dim3(Bz * Tz), blk, 0, stream>>>(IDS, out + (size_t)Bz * 2 * Tz * Dz);
}

// Round 2
// 2719.814 us; speedup vs baseline: 1.2272x; 1.2272x over previous
//
#include <hip/hip_runtime.h>
#include <math.h>

// Problem constants (fixed by setup_inputs)
#define Bz 8
#define Tz 1024
#define Dz 512
#define FFz 2048
#define Hz 8
#define DHz 64
#define Mz (Bz * Tz)  // 8192 rows

// ---------------------------------------------------------------------------
// zero fill (colsum accumulators must start at 0; ws is poisoned 0xAA)
// ---------------------------------------------------------------------------
__global__ __launch_bounds__(256) void zero_kernel(float* __restrict__ p, int n) {
  int i = blockIdx.x * 256 + threadIdx.x;
  if (i < n) p[i] = 0.f;
}

// ---------------------------------------------------------------------------
// fp32 GEMM: C[M,N] = A[M,K] @ B[K,N], all row-major, optional fused ReLU.
// 128x128 tile, BK=16, 256 threads, 8x8 micro-tile per thread. (unchanged)
// ---------------------------------------------------------------------------
__global__ __launch_bounds__(256) void gemm_kernel(
    const float* __restrict__ A, const float* __restrict__ Bm,
    float* __restrict__ C, int M, int N, int K, int relu)
{
  __shared__ float As[16][132];  // [k][m]
  __shared__ float Bs[16][132];  // [k][n]
  const int tid = threadIdx.x;
  const int bm = blockIdx.y * 128;
  const int bn = blockIdx.x * 128;
  const int tx = tid & 15, ty = tid >> 4;
  float acc[8][8];
#pragma unroll
  for (int i = 0; i < 8; ++i)
#pragma unroll
    for (int j = 0; j < 8; ++j) acc[i][j] = 0.f;

  for (int k0 = 0; k0 < K; k0 += 16) {
#pragma unroll
    for (int i = 0; i < 2; ++i) {
      int idx = tid + i * 256;
      int r = idx >> 2, kv = (idx & 3) << 2;
      float4 a = *reinterpret_cast<const float4*>(&A[(size_t)(bm + r) * K + k0 + kv]);
      As[kv + 0][r] = a.x; As[kv + 1][r] = a.y; As[kv + 2][r] = a.z; As[kv + 3][r] = a.w;
      int kk = idx >> 5, nv = (idx & 31) << 2;
      *reinterpret_cast<float4*>(&Bs[kk][nv]) =
          *reinterpret_cast<const float4*>(&Bm[(size_t)(k0 + kk) * N + bn + nv]);
    }
    __syncthreads();
#pragma unroll
    for (int kk = 0; kk < 16; ++kk) {
      float ar[8], br[8];
#pragma unroll
      for (int i = 0; i < 8; ++i) ar[i] = As[kk][ty * 8 + i];
#pragma unroll
      for (int j = 0; j < 4; ++j) {
        br[j]     = Bs[kk][tx * 4 + j];
        br[4 + j] = Bs[kk][64 + tx * 4 + j];
      }
#pragma unroll
      for (int i = 0; i < 8; ++i)
#pragma unroll
        for (int j = 0; j < 8; ++j) acc[i][j] += ar[i] * br[j];
    }
    __syncthreads();
  }
#pragma unroll
  for (int i = 0; i < 8; ++i) {
    size_t row = (size_t)(bm + ty * 8 + i);
    float4 v0, v1;
    v0.x = acc[i][0]; v0.y = acc[i][1]; v0.z = acc[i][2]; v0.w = acc[i][3];
    v1.x = acc[i][4]; v1.y = acc[i][5]; v1.z = acc[i][6]; v1.w = acc[i][7];
    if (relu) {
      v0.x = fmaxf(v0.x, 0.f); v0.y = fmaxf(v0.y, 0.f); v0.z = fmaxf(v0.z, 0.f); v0.w = fmaxf(v0.w, 0.f);
      v1.x = fmaxf(v1.x, 0.f); v1.y = fmaxf(v1.y, 0.f); v1.z = fmaxf(v1.z, 0.f); v1.w = fmaxf(v1.w, 0.f);
    }
    *reinterpret_cast<float4*>(&C[row * N + bn + tx * 4]) = v0;
    *reinterpret_cast<float4*>(&C[row * N + bn + 64 + tx * 4]) = v1;
  }
}

// ---------------------------------------------------------------------------
// Fused attention v2: 64-query tile per block, 16 key-tiles of 64.
// Two passes, no max subtraction (scores bounded; exp(s) fp32-safe):
//   pass 1: S = QK^T (register 8q x 2k micro-tiles), Z row-sums of exp.
//   pass 2: recompute S, P = exp(s)/Z exactly, LDS colsum + P^T staging,
//           PV GEMM (8q x 2d micro-tiles), O accumulated across tiles.
// K prefetched into registers across each GEMM (vmcnt overlaps compute).
// LDS staging patterns arranged for <=2-way bank aliasing (free, m136).
// ---------------------------------------------------------------------------
template <bool MASKED>
__global__ __launch_bounds__(256) void attn_kernel(
    const float* __restrict__ Qf, const float* __restrict__ Kf, const float* __restrict__ Vf,
    const int* __restrict__ ids, float* __restrict__ ctx, float* __restrict__ colsum)
{
  __shared__ float Qs[64][68];   // Q^T: [d][q], staged once
  __shared__ float KVs[64][68];  // K^T: [d][k] during S; V: [k][d] during PV
  __shared__ float Pt[64][68];   // P^T: [k][q]
  __shared__ float csb[1024];    // per-key colsum accumulator (block-local)
  __shared__ int   kid[64];
  __shared__ int   qidb[64];

  const int tid = threadIdx.x;
  const int qt = blockIdx.x & 15;          // q-tile fastest -> same (b,h) adjacent
  const int h  = (blockIdx.x >> 4) & 7;
  const int b  = blockIdx.x >> 7;
  const int q0 = qt * 64;
  const int ty = tid >> 5;                 // 0..7: q rows ty*8 .. ty*8+7
  const int tx = tid & 31;                 // 0..31: keys/dims 2*tx, 2*tx+1
  const size_t bT = (size_t)b * Tz;

  // staging map: row sr (0..63), d-offset sd + 16*i. Consecutive 4 lanes read
  // one 64B row chunk; transposed scalar writes land 2-way per bank (free).
  const int sr = tid >> 2;
  const int sd = (tid & 3) << 2;

  {  // stage Q^T once; zero csb; stage qid
    const float* qsrc = &Qf[(bT + q0 + sr) * Dz + h * DHz];
#pragma unroll
    for (int i = 0; i < 4; ++i) {
      int d0 = sd + i * 16;
      float4 v = *reinterpret_cast<const float4*>(&qsrc[d0]);
      Qs[d0 + 0][sr] = v.x; Qs[d0 + 1][sr] = v.y; Qs[d0 + 2][sr] = v.z; Qs[d0 + 3][sr] = v.w;
    }
    if (MASKED && tid < 64) qidb[tid] = ids[bT + q0 + tid];
    for (int i = tid; i < 1024; i += 256) csb[i] = 0.f;
  }
  __syncthreads();

  int qidr[8];
  if (MASKED) {
#pragma unroll
    for (int r = 0; r < 8; ++r) qidr[r] = qidb[ty * 8 + r];
  }

  const float* kbase = Kf + (bT + sr) * Dz + h * DHz + sd;
  const float* vbase = Vf + (bT + sr) * Dz + h * DHz + sd;

  // ---------------- pass 1: Z row sums ----------------
  float z[8];
#pragma unroll
  for (int r = 0; r < 8; ++r) z[r] = 0.f;

  float4 kreg[4];
#pragma unroll
  for (int i = 0; i < 4; ++i) kreg[i] = *reinterpret_cast<const float4*>(kbase + i * 16);
  int kidp = (MASKED && tid < 64) ? ids[bT + tid] : 0;

  for (int t = 0; t < 16; ++t) {
#pragma unroll
    for (int i = 0; i < 4; ++i) {  // K^T scalar staging: 2-way banks, free
      int d0 = sd + i * 16;
      KVs[d0 + 0][sr] = kreg[i].x; KVs[d0 + 1][sr] = kreg[i].y;
      KVs[d0 + 2][sr] = kreg[i].z; KVs[d0 + 3][sr] = kreg[i].w;
    }
    if (MASKED && tid < 64) kid[tid] = kidp;
    __syncthreads();
    if (t < 15) {  // prefetch next tile; vmcnt waits overlap the GEMM
      const float* kb2 = kbase + (size_t)(t + 1) * 64 * Dz;
#pragma unroll
      for (int i = 0; i < 4; ++i) kreg[i] = *reinterpret_cast<const float4*>(kb2 + i * 16);
      if (MASKED && tid < 64) kidp = ids[bT + (t + 1) * 64 + tid];
    }
    float s[8][2];
#pragma unroll
    for (int r = 0; r < 8; ++r) s[r][0] = s[r][1] = 0.f;
#pragma unroll 4
    for (int d = 0; d < 64; ++d) {
      float4 qa = *reinterpret_cast<const float4*>(&Qs[d][ty * 8]);      // broadcast
      float4 qb = *reinterpret_cast<const float4*>(&Qs[d][ty * 8 + 4]);  // broadcast
      float2 kv = *reinterpret_cast<const float2*>(&KVs[d][tx * 2]);     // contiguous
      s[0][0] += qa.x * kv.x; s[0][1] += qa.x * kv.y;
      s[1][0] += qa.y * kv.x; s[1][1] += qa.y * kv.y;
      s[2][0] += qa.z * kv.x; s[2][1] += qa.z * kv.y;
      s[3][0] += qa.w * kv.x; s[3][1] += qa.w * kv.y;
      s[4][0] += qb.x * kv.x; s[4][1] += qb.x * kv.y;
      s[5][0] += qb.y * kv.x; s[5][1] += qb.y * kv.y;
      s[6][0] += qb.z * kv.x; s[6][1] += qb.z * kv.y;
      s[7][0] += qb.w * kv.x; s[7][1] += qb.w * kv.y;
    }
    int ka = 0, kb = 0;
    if (MASKED) { ka = kid[tx * 2]; kb = kid[tx * 2 + 1]; }
#pragma unroll
    for (int r = 0; r < 8; ++r) {
      float e0 = __expf(s[r][0] * 0.125f);
      float e1 = __expf(s[r][1] * 0.125f);
      if (MASKED) {
        if (qidr[r] != ka) e0 = 0.f;
        if (qidr[r] != kb) e1 = 0.f;
      }
      z[r] += e0 + e1;
    }
    __syncthreads();
  }
  // reduce Z across the 32 tx lanes (stays within ty group: xor < 32)
#pragma unroll
  for (int w = 1; w < 32; w <<= 1) {
#pragma unroll
    for (int r = 0; r < 8; ++r) z[r] += __shfl_xor(z[r], w);
  }
  float invz[8];
#pragma unroll
  for (int r = 0; r < 8; ++r) invz[r] = 1.f / z[r];

  // ---------------- pass 2: P, colsum, PV ----------------
  float o[8][2];
#pragma unroll
  for (int r = 0; r < 8; ++r) o[r][0] = o[r][1] = 0.f;

#pragma unroll
  for (int i = 0; i < 4; ++i) kreg[i] = *reinterpret_cast<const float4*>(kbase + i * 16);
  if (MASKED && tid < 64) kidp = ids[bT + tid];
  float4 vreg[4];

  for (int t = 0; t < 16; ++t) {
#pragma unroll
    for (int i = 0; i < 4; ++i) {  // K^T staging
      int d0 = sd + i * 16;
      KVs[d0 + 0][sr] = kreg[i].x; KVs[d0 + 1][sr] = kreg[i].y;
      KVs[d0 + 2][sr] = kreg[i].z; KVs[d0 + 3][sr] = kreg[i].w;
    }
    if (MASKED && tid < 64) kid[tid] = kidp;
    __syncthreads();
    {  // prefetch this tile's V; consumed after the S GEMM
      const float* vb2 = vbase + (size_t)t * 64 * Dz;
#pragma unroll
      for (int i = 0; i < 4; ++i) vreg[i] = *reinterpret_cast<const float4*>(vb2 + i * 16);
    }
    float s[8][2];
#pragma unroll
    for (int r = 0; r < 8; ++r) s[r][0] = s[r][1] = 0.f;
#pragma unroll 4
    for (int d = 0; d < 64; ++d) {
      float4 qa = *reinterpret_cast<const float4*>(&Qs[d][ty * 8]);
      float4 qb = *reinterpret_cast<const float4*>(&Qs[d][ty * 8 + 4]);
      float2 kv = *reinterpret_cast<const float2*>(&KVs[d][tx * 2]);
      s[0][0] += qa.x * kv.x; s[0][1] += qa.x * kv.y;
      s[1][0] += qa.y * kv.x; s[1][1] += qa.y * kv.y;
      s[2][0] += qa.z * kv.x; s[2][1] += qa.z * kv.y;
      s[3][0] += qa.w * kv.x; s[3][1] += qa.w * kv.y;
      s[4][0] += qb.x * kv.x; s[4][1] += qb.x * kv.y;
      s[5][0] += qb.y * kv.x; s[5][1] += qb.y * kv.y;
      s[6][0] += qb.z * kv.x; s[6][1] += qb.z * kv.y;
      s[7][0] += qb.w * kv.x; s[7][1] += qb.w * kv.y;
    }
    int ka = 0, kb = 0;
    if (MASKED) { ka = kid[tx * 2]; kb = kid[tx * 2 + 1]; }
    float p[8][2];
#pragma unroll
    for (int r = 0; r < 8; ++r) {
      float e0 = __expf(s[r][0] * 0.125f);
      float e1 = __expf(s[r][1] * 0.125f);
      if (MASKED) {
        if (qidr[r] != ka) e0 = 0.f;
        if (qidr[r] != kb) e1 = 0.f;
      }
      p[r][0] = e0 * invz[r];
      p[r][1] = e1 * invz[r];
    }
    __syncthreads();  // S readers done: safe to overwrite KVs with V
#pragma unroll
    for (int i = 0; i < 4; ++i)  // V natural [k][d], float4 writes
      *reinterpret_cast<float4*>(&KVs[sr][sd + i * 16]) = vreg[i];
    // P^T staging
    float4 w0, w1, w2, w3;
    w0.x = p[0][0]; w0.y = p[1][0]; w0.z = p[2][0]; w0.w = p[3][0];
    w1.x = p[4][0]; w1.y = p[5][0]; w1.z = p[6][0]; w1.w = p[7][0];
    w2.x = p[0][1]; w2.y = p[1][1]; w2.z = p[2][1]; w2.w = p[3][1];
    w3.x = p[4][1]; w3.y = p[5][1]; w3.z = p[6][1]; w3.w = p[7][1];
    *reinterpret_cast<float4*>(&Pt[tx * 2][ty * 8])     = w0;
    *reinterpret_cast<float4*>(&Pt[tx * 2][ty * 8 + 4]) = w1;
    *reinterpret_cast<float4*>(&Pt[tx * 2 + 1][ty * 8])     = w2;
    *reinterpret_cast<float4*>(&Pt[tx * 2 + 1][ty * 8 + 4]) = w3;
    // colsum partials: sum over this thread's 8 q, fold ty-pairs via xor-32,
    // then one LDS atomic per key per wave (4-way serialization, cheap)
    float c0 = p[0][0] + p[1][0] + p[2][0] + p[3][0] + p[4][0] + p[5][0] + p[6][0] + p[7][0];
    float c1 = p[0][1] + p[1][1] + p[2][1] + p[3][1] + p[4][1] + p[5][1] + p[6][1] + p[7][1];
    c0 += __shfl_xor(c0, 32);
    c1 += __shfl_xor(c1, 32);
    if ((tid & 32) == 0) {
      atomicAdd(&csb[t * 64 + tx * 2], c0);
      atomicAdd(&csb[t * 64 + tx * 2 + 1], c1);
    }
    __syncthreads();
    if (t < 15) {  // prefetch next K tile; waits overlap the PV GEMM
      const float* kb2 = kbase + (size_t)(t + 1) * 64 * Dz;
#pragma unroll
      for (int i = 0; i < 4; ++i) kreg[i] = *reinterpret_cast<const float4*>(kb2 + i * 16);
      if (MASKED && tid < 64) kidp = ids[bT + (t + 1) * 64 + tid];
    }
#pragma unroll 4
    for (int kk = 0; kk < 64; ++kk) {
      float4 pa = *reinterpret_cast<const float4*>(&Pt[kk][ty * 8]);      // broadcast
      float4 pb = *reinterpret_cast<const float4*>(&Pt[kk][ty * 8 + 4]);  // broadcast
      float2 vv = *reinterpret_cast<const float2*>(&KVs[kk][tx * 2]);     // contiguous
      o[0][0] += pa.x * vv.x; o[0][1] += pa.x * vv.y;
      o[1][0] += pa.y * vv.x; o[1][1] += pa.y * vv.y;
      o[2][0] += pa.z * vv.x; o[2][1] += pa.z * vv.y;
      o[3][0] += pa.w * vv.x; o[3][1] += pa.w * vv.y;
      o[4][0] += pb.x * vv.x; o[4][1] += pb.x * vv.y;
      o[5][0] += pb.y * vv.x; o[5][1] += pb.y * vv.y;
      o[6][0] += pb.z * vv.x; o[6][1] += pb.z * vv.y;
      o[7][0] += pb.w * vv.x; o[7][1] += pb.w * vv.y;
    }
    __syncthreads();
  }

  // epilogue: ctx writes (P already normalized) + colsum flush
#pragma unroll
  for (int r = 0; r < 8; ++r) {
    float2 ov; ov.x = o[r][0]; ov.y = o[r][1];
    *reinterpret_cast<float2*>(&ctx[(bT + q0 + ty * 8 + r) * Dz + h * DHz + tx * 2]) = ov;
  }
  __syncthreads();
#pragma unroll
  for (int i = 0; i < 4; ++i) {
    int k = tid + i * 256;
    atomicAdd(&colsum[bT + k], csb[k] * (1.f / Hz));
  }
}

// ---------------------------------------------------------------------------
// out = LayerNorm(resid + delta), D=512, no affine. One 256-thread block/row.
// ---------------------------------------------------------------------------
__global__ __launch_bounds__(256) void ln_kernel(const float* __restrict__ resid,
    const float* __restrict__ delta, float* __restrict__ out)
{
  const size_t base = (size_t)blockIdx.x * Dz;
  const int tid = threadIdx.x;
  float x0 = resid[base + tid] + delta[base + tid];
  float x1 = resid[base + tid + 256] + delta[base + tid + 256];
  __shared__ float red[4];
  float s = x0 + x1;
#pragma unroll
  for (int off = 32; off; off >>= 1) s += __shfl_down(s, off);
  if ((tid & 63) == 0) red[tid >> 6] = s;
  __syncthreads();
  const float mean = (red[0] + red[1] + red[2] + red[3]) * (1.f / Dz);
  __syncthreads();
  float d0 = x0 - mean, d1 = x1 - mean;
  float v = d0 * d0 + d1 * d1;
#pragma unroll
  for (int off = 32; off; off >>= 1) v += __shfl_down(v, off);
  if ((tid & 63) == 0) red[tid >> 6] = v;
  __syncthreads();
  const float var = (red[0] + red[1] + red[2] + red[3]) * (1.f / Dz);
  const float rstd = rsqrtf(var + 1e-5f);
  out[base + tid] = d0 * rstd;
  out[base + tid + 256] = d1 * rstd;
}

// ---------------------------------------------------------------------------
// Per batch: min-max normalize colsum, threshold 0.5, run-length window scan.
// ---------------------------------------------------------------------------
__global__ __launch_bounds__(256) void window_ids_kernel(const float* __restrict__ cs,
    int* __restrict__ ids, int* __restrict__ wst, int* __restrict__ nwin)
{
  const int b = blockIdx.x, tid = threadIdx.x;
  __shared__ float vals[Tz];
  __shared__ unsigned char wb[Tz];
  __shared__ int sids[Tz];
  __shared__ float rmin[4], rmax[4];
  float mn = INFINITY, mx = -INFINITY;
  for (int t = tid; t < Tz; t += 256) {
    float v = cs[b * Tz + t];
    vals[t] = v;
    mn = fminf(mn, v); mx = fmaxf(mx, v);
  }
#pragma unroll
  for (int off = 32; off; off >>= 1) {
    mn = fminf(mn, __shfl_down(mn, off));
    mx = fmaxf(mx, __shfl_down(mx, off));
  }
  if ((tid & 63) == 0) { rmin[tid >> 6] = mn; rmax[tid >> 6] = mx; }
  __syncthreads();
  mn = fminf(fminf(rmin[0], rmin[1]), fminf(rmin[2], rmin[3]));
  mx = fmaxf(fmaxf(rmax[0], rmax[1]), fmaxf(rmax[2], rmax[3]));
  const float inv = 1.f / (mx - mn + 1e-8f);
  for (int t = tid; t < Tz; t += 256) wb[t] = (((vals[t] - mn) * inv) >= 0.5f) ? 1 : 0;
  __syncthreads();
  if (tid == 0) {
    int cur = wb[0], start = 0, wid = 0;
    sids[0] = 0;
    wst[b * (Tz + 1)] = 0;
    for (int t = 1; t < Tz; ++t) {
      int wt = wb[t];
      if (wt != cur) {
        cur = wt;
        if (start + 1 != t) {
          start = t;
          ++wid;
          wst[b * (Tz + 1) + wid] = t;
        }
      }
      sids[t] = wid;
    }
    nwin[b] = wid + 1;
    wst[b * (Tz + 1) + wid + 1] = Tz;
  }
  __syncthreads();
  for (int t = tid; t < Tz; t += 256) ids[b * Tz + t] = sids[t];
}

// ---------------------------------------------------------------------------
// wl[b,:] = softmax over keys of layer-2 colsum (already includes 1/H).
// ---------------------------------------------------------------------------
__global__ __launch_bounds__(256) void wl_softmax_kernel(const float* __restrict__ cs,
                                                         float* __restrict__ wl)
{
  const int b = blockIdx.x, tid = threadIdx.x;
  __shared__ float vals[Tz];
  __shared__ float red[4];
  float mx = -INFINITY;
  for (int t = tid; t < Tz; t += 256) {
    float v = cs[b * Tz + t];
    vals[t] = v;
    mx = fmaxf(mx, v);
  }
#pragma unroll
  for (int off = 32; off; off >>= 1) mx = fmaxf(mx, __shfl_down(mx, off));
  if ((tid & 63) == 0) red[tid >> 6] = mx;
  __syncthreads();
  mx = fmaxf(fmaxf(red[0], red[1]), fmaxf(red[2], red[3]));
  __syncthreads();
  float se = 0.f;
  for (int t = tid; t < Tz; t += 256) {
    float e = expf(vals[t] - mx);
    vals[t] = e;
    se += e;
  }
#pragma unroll
  for (int off = 32; off; off >>= 1) se += __shfl_down(se, off);
  if ((tid & 63) == 0) red[tid >> 6] = se;
  __syncthreads();
  const float inv = 1.f / (red[0] + red[1] + red[2] + red[3]);
  for (int t = tid; t < Tz; t += 256) wl[b * Tz + t] = vals[t] * inv;
}

// ---------------------------------------------------------------------------
// word_tokens rows of output 0.
// ---------------------------------------------------------------------------
__global__ __launch_bounds__(256) void word_tokens_kernel(const float* __restrict__ outl,
    const float* __restrict__ wl, const int* __restrict__ wst, const int* __restrict__ nwin,
    float* __restrict__ out)
{
  const int w = blockIdx.x & (Tz - 1);
  const int b = blockIdx.x >> 10;
  const int tid = threadIdx.x;
  float a0 = 0.f, a1 = 0.f;
  if (w < nwin[b]) {
    const int s = wst[b * (Tz + 1) + w], e = wst[b * (Tz + 1) + w + 1];
    for (int t = s; t < e; ++t) {
      const float sc = wl[b * Tz + t];
      const float* p = &outl[((size_t)(b * Tz + t)) * Dz];
      a0 += p[tid] * sc;
      a1 += p[tid + 256] * sc;
    }
  }
  float* o = &out[((size_t)(b * 2 * Tz + w)) * Dz];
  o[tid] = a0;
  o[tid + 256] = a1;
}

// ---------------------------------------------------------------------------
// out0 rows [T, 2T): copy of the original input x.
// ---------------------------------------------------------------------------
__global__ __launch_bounds__(256) void copy_x_kernel(const float* __restrict__ x,
                                                     float* __restrict__ out)
{
  size_t i = (size_t)blockIdx.x * 256 + threadIdx.x;
  size_t idx = i * 4;
  size_t rowi = idx >> 9;
  size_t d = idx & 511;
  size_t b = rowi >> 10, t = rowi & 1023;
  float4 v = *reinterpret_cast<const float4*>(&x[idx]);
  *reinterpret_cast<float4*>(&out[(((b * 2 * Tz) + Tz + t) << 9) + d]) = v;
}

// ---------------------------------------------------------------------------
// Output 1: window_mapping[b, w, j] = (ids[b,j] == w).
// ---------------------------------------------------------------------------
__global__ __launch_bounds__(256) void winmap_kernel(const int* __restrict__ ids,
                                                     float* __restrict__ out2)
{
  const int w = blockIdx.x & (Tz - 1);
  const int b = blockIdx.x >> 10;
  const int tid = threadIdx.x;
  const int j = tid * 4;
  int4 id4 = *reinterpret_cast<const int4*>(&ids[b * Tz + j]);
  float4 v;
  v.x = (id4.x == w) ? 1.f : 0.f;
  v.y = (id4.y == w) ? 1.f : 0.f;
  v.z = (id4.z == w) ? 1.f : 0.f;
  v.w = (id4.w == w) ? 1.f : 0.f;
  *reinterpret_cast<float4*>(&out2[((size_t)(b * Tz + w)) * Tz + j]) = v;
}

// ---------------------------------------------------------------------------
// Orchestration.
// ---------------------------------------------------------------------------
extern "C" void kernel_launch(void* const* d_in, const int* in_sizes, int n_in,
                              void* d_out, int out_size, void* d_ws, size_t ws_size,
                              hipStream_t stream)
{
  (void)in_sizes; (void)n_in; (void)out_size; (void)ws_size;
  const float* x     = (const float*)d_in[0];
  const float* vqkv  = (const float*)d_in[1];
  const float* voutw = (const float*)d_in[2];
  const float* vw1   = (const float*)d_in[3];
  const float* vw2   = (const float*)d_in[4];
  const float* lqkv  = (const float*)d_in[5];
  const float* loutw = (const float*)d_in[6];
  const float* lw1   = (const float*)d_in[7];
  const float* lw2   = (const float*)d_in[8];
  float* out = (float*)d_out;
  float* ws  = (float*)d_ws;

  float* Q    = ws + 0;
  float* Kb   = ws + 4194304;
  float* Vb   = ws + 8388608;
  float* CTX  = ws + 12582912;
  float* HID  = ws + 0;          // aliases Q..CTX during FFN
  float* Y1   = ws + 16777216;
  float* PROJ = ws + 20971520;
  float* OUTV = ws + 25165824;
  float* OUTL = ws + 29360128;
  float* CS1  = ws + 33554432;
  float* CS2  = ws + 33562624;
  float* WL   = ws + 33570816;
  int*   IDS  = (int*)(ws + 33579008);
  int*   WST  = (int*)(ws + 33587200);
  int*   NWIN = (int*)(ws + 33595400);

  dim3 blk(256);
  zero_kernel<<<dim3(64), blk, 0, stream>>>(CS1, 16384);

  auto gemm = [&](const float* A, const float* Bm, float* C, int M, int N, int K, int relu) {
    gemm_kernel<<<dim3(N / 128, M / 128), blk, 0, stream>>>(A, Bm, C, M, N, K, relu);
  };

  // ---------------- layer 1 (vanilla) ----------------
  gemm(x, vqkv + 0 * Dz * Dz, Q,  Mz, Dz, Dz, 0);
  gemm(x, vqkv + 1 * Dz * Dz, Kb, Mz, Dz, Dz, 0);
  gemm(x, vqkv + 2 * Dz * Dz, Vb, Mz, Dz, Dz, 0);
  attn_kernel<false><<<dim3(Bz * Hz * (Tz / 64)), blk, 0, stream>>>(Q, Kb, Vb, nullptr, CTX, CS1);
  gemm(CTX, voutw, PROJ, Mz, Dz, Dz, 0);
  ln_kernel<<<dim3(Mz), blk, 0, stream>>>(x, PROJ, Y1);
  gemm(Y1, vw1, HID, Mz, FFz, Dz, 1);
  gemm(HID, vw2, PROJ, Mz, Dz, FFz, 0);
  ln_kernel<<<dim3(Mz), blk, 0, stream>>>(Y1, PROJ, OUTV);

  // ---------------- dynamic window generation ----------------
  window_ids_kernel<<<dim3(Bz), blk, 0, stream>>>(CS1, IDS, WST, NWIN);

  // ---------------- layer 2 (block-diagonal window mask) ----------------
  gemm(OUTV, lqkv + 0 * Dz * Dz, Q,  Mz, Dz, Dz, 0);
  gemm(OUTV, lqkv + 1 * Dz * Dz, Kb, Mz, Dz, Dz, 0);
  gemm(OUTV, lqkv + 2 * Dz * Dz, Vb, Mz, Dz, Dz, 0);
  attn_kernel<true><<<dim3(Bz * Hz * (Tz / 64)), blk, 0, stream>>>(Q, Kb, Vb, IDS, CTX, CS2);
  gemm(CTX, loutw, PROJ, Mz, Dz, Dz, 0);
  ln_kernel<<<dim3(Mz), blk, 0, stream>>>(OUTV, PROJ, Y1);
  gemm(Y1, lw1, HID, Mz, FFz, Dz, 1);
  gemm(HID, lw2, PROJ, Mz, Dz, FFz, 0);
  ln_kernel<<<dim3(Mz), blk, 0, stream>>>(Y1, PROJ, OUTL);

  // ---------------- pooling + outputs ----------------
  wl_softmax_kernel<<<dim3(Bz), blk, 0, stream>>>(CS2, WL);
  word_tokens_kernel<<<dim3(Bz * Tz), blk, 0, stream>>>(OUTL, WL, WST, NWIN, out);
  copy_x_kernel<<<dim3(Bz * Tz * Dz / 1024), blk, 0, stream>>>(x, out);
  winmap_kernel<<<dim3(Bz * Tz), blk, 0, stream>>>(IDS, out + (size_t)Bz * 2 * Tz * Dz);
}

// Round 3
// 1642.344 us; speedup vs baseline: 2.0322x; 1.6561x over previous
//
#include <hip/hip_runtime.h>
#include <math.h>

// Problem constants (fixed by setup_inputs)
#define Bz 8
#define Tz 1024
#define Dz 512
#define FFz 2048
#define Hz 8
#define DHz 64
#define Mz (Bz * Tz)  // 8192 rows

typedef __attribute__((ext_vector_type(8))) short short8;   // 8 bf16 (4 VGPRs)
typedef __attribute__((ext_vector_type(4))) float f32x4;    // MFMA accumulator

__device__ inline unsigned short f2bf(float f) {  // RNE fp32 -> bf16
  unsigned u = __builtin_bit_cast(unsigned, f);
  return (unsigned short)((u + 0x7FFFu + ((u >> 16) & 1u)) >> 16);
}

// ---------------------------------------------------------------------------
// zero fill (colsum accumulators must start at 0; ws is poisoned 0xAA)
// ---------------------------------------------------------------------------
__global__ __launch_bounds__(256) void zero_kernel(float* __restrict__ p, int n) {
  int i = blockIdx.x * 256 + threadIdx.x;
  if (i < n) p[i] = 0.f;
}

// ---------------------------------------------------------------------------
// Weight convert+transpose: in fp32 [K,N] -> out bf16 [N,K] (so MFMA
// B-fragments are contiguous 16B in global; weights stay L2-resident).
// ---------------------------------------------------------------------------
__global__ __launch_bounds__(256) void wconv_kernel(const float* __restrict__ in,
    unsigned short* __restrict__ out, int K, int N)
{
  __shared__ float t[32][33];
  const int bn = blockIdx.x * 32, bk = blockIdx.y * 32;
  const int tx = threadIdx.x & 31, ty = threadIdx.x >> 5;  // ty 0..7
#pragma unroll
  for (int i = 0; i < 32; i += 8) t[ty + i][tx] = in[(size_t)(bk + ty + i) * N + bn + tx];
  __syncthreads();
#pragma unroll
  for (int i = 0; i < 32; i += 8)
    out[(size_t)(bn + ty + i) * K + bk + tx] = f2bf(t[tx][ty + i]);
}

// ---------------------------------------------------------------------------
// Flat fp32 -> bf16 convert (for x). 4 elems/thread.
// ---------------------------------------------------------------------------
__global__ __launch_bounds__(256) void fconv_kernel(const float* __restrict__ in,
    unsigned short* __restrict__ out, int n4)
{
  int i = blockIdx.x * 256 + threadIdx.x;
  if (i >= n4) return;
  float4 v = *reinterpret_cast<const float4*>(&in[(size_t)i * 4]);
  ushort4 o;
  o.x = f2bf(v.x); o.y = f2bf(v.y); o.z = f2bf(v.z); o.w = f2bf(v.w);
  *reinterpret_cast<ushort4*>(&out[(size_t)i * 4]) = o;
}

// ---------------------------------------------------------------------------
// bf16 MFMA GEMM: C[M,N] = A[M,K] @ B[K,N]; A bf16 [M,K] row-major,
// B pre-transposed bf16 [N,K]. One wave per block computing a 64x64 tile
// (4x4 grid of 16x16x32 MFMAs), fragments loaded directly from global
// (no LDS, no barriers; B-frags are L2-hot). Double-buffered K loop.
// Output: fp32 (Cf) or bf16 (Cbf, optional fused ReLU).
// ---------------------------------------------------------------------------
__global__ __launch_bounds__(64) void mfma_gemm_kernel(
    const unsigned short* __restrict__ A, const unsigned short* __restrict__ BT,
    float* __restrict__ Cf, unsigned short* __restrict__ Cbf,
    int K, int N, int relu)
{
  const int l = threadIdx.x;               // 0..63
  const int m0 = blockIdx.y * 64;
  const int n0 = blockIdx.x * 64;
  const int mr = l & 15, quad = l >> 4;    // frag row/col = mr, k-offset = quad*8

  f32x4 acc[4][4];
  const f32x4 zero = {0.f, 0.f, 0.f, 0.f};
#pragma unroll
  for (int i = 0; i < 4; ++i)
#pragma unroll
    for (int j = 0; j < 4; ++j) acc[i][j] = zero;

  const unsigned short* Ap = A + (size_t)(m0 + mr) * K + quad * 8;
  const unsigned short* Bp = BT + (size_t)(n0 + mr) * K + quad * 8;

  short8 a[4], b[4], an[4], bn[4];
#pragma unroll
  for (int i = 0; i < 4; ++i) {
    a[i] = *reinterpret_cast<const short8*>(Ap + (size_t)i * 16 * K);
    b[i] = *reinterpret_cast<const short8*>(Bp + (size_t)i * 16 * K);
  }
  for (int k0 = 0; k0 < K; k0 += 32) {
    if (k0 + 32 < K) {
#pragma unroll
      for (int i = 0; i < 4; ++i) {
        an[i] = *reinterpret_cast<const short8*>(Ap + (size_t)i * 16 * K + k0 + 32);
        bn[i] = *reinterpret_cast<const short8*>(Bp + (size_t)i * 16 * K + k0 + 32);
      }
    }
#pragma unroll
    for (int i = 0; i < 4; ++i)
#pragma unroll
      for (int j = 0; j < 4; ++j)
        acc[i][j] = __builtin_amdgcn_mfma_f32_16x16x32_bf16(a[i], b[j], acc[i][j], 0, 0, 0);
#pragma unroll
    for (int i = 0; i < 4; ++i) { a[i] = an[i]; b[i] = bn[i]; }
  }

  // C/D layout: col = lane&15, row = quad*4 + reg   [measured: m89/m91]
#pragma unroll
  for (int i = 0; i < 4; ++i)
#pragma unroll
    for (int j = 0; j < 4; ++j) {
      const int col = n0 + j * 16 + mr;
#pragma unroll
      for (int rr = 0; rr < 4; ++rr) {
        const int row = m0 + i * 16 + quad * 4 + rr;
        float v = acc[i][j][rr];
        if (relu) v = fmaxf(v, 0.f);
        if (Cf)  Cf[(size_t)row * N + col] = v;
        else     Cbf[(size_t)row * N + col] = f2bf(v);
      }
    }
}

// ---------------------------------------------------------------------------
// fp32 GEMM (kept ONLY for layer-1 Q,K: the window-mask bits depend on these
// and must stay bit-identical fp32). 128x128 tile, BK=16, 8x8 micro-tile.
// ---------------------------------------------------------------------------
__global__ __launch_bounds__(256) void gemm_kernel(
    const float* __restrict__ A, const float* __restrict__ Bm,
    float* __restrict__ C, int M, int N, int K)
{
  __shared__ float As[16][132];  // [k][m]
  __shared__ float Bs[16][132];  // [k][n]
  const int tid = threadIdx.x;
  const int bm = blockIdx.y * 128;
  const int bn = blockIdx.x * 128;
  const int tx = tid & 15, ty = tid >> 4;
  float acc[8][8];
#pragma unroll
  for (int i = 0; i < 8; ++i)
#pragma unroll
    for (int j = 0; j < 8; ++j) acc[i][j] = 0.f;

  for (int k0 = 0; k0 < K; k0 += 16) {
#pragma unroll
    for (int i = 0; i < 2; ++i) {
      int idx = tid + i * 256;
      int r = idx >> 2, kv = (idx & 3) << 2;
      float4 a = *reinterpret_cast<const float4*>(&A[(size_t)(bm + r) * K + k0 + kv]);
      As[kv + 0][r] = a.x; As[kv + 1][r] = a.y; As[kv + 2][r] = a.z; As[kv + 3][r] = a.w;
      int kk = idx >> 5, nv = (idx & 31) << 2;
      *reinterpret_cast<float4*>(&Bs[kk][nv]) =
          *reinterpret_cast<const float4*>(&Bm[(size_t)(k0 + kk) * N + bn + nv]);
    }
    __syncthreads();
#pragma unroll
    for (int kk = 0; kk < 16; ++kk) {
      float ar[8], br[8];
#pragma unroll
      for (int i = 0; i < 8; ++i) ar[i] = As[kk][ty * 8 + i];
#pragma unroll
      for (int j = 0; j < 4; ++j) {
        br[j]     = Bs[kk][tx * 4 + j];
        br[4 + j] = Bs[kk][64 + tx * 4 + j];
      }
#pragma unroll
      for (int i = 0; i < 8; ++i)
#pragma unroll
        for (int j = 0; j < 8; ++j) acc[i][j] += ar[i] * br[j];
    }
    __syncthreads();
  }
#pragma unroll
  for (int i = 0; i < 8; ++i) {
    size_t row = (size_t)(bm + ty * 8 + i);
    float4 v0, v1;
    v0.x = acc[i][0]; v0.y = acc[i][1]; v0.z = acc[i][2]; v0.w = acc[i][3];
    v1.x = acc[i][4]; v1.y = acc[i][5]; v1.z = acc[i][6]; v1.w = acc[i][7];
    *reinterpret_cast<float4*>(&C[row * N + bn + tx * 4]) = v0;
    *reinterpret_cast<float4*>(&C[row * N + bn + 64 + tx * 4]) = v1;
  }
}

// ---------------------------------------------------------------------------
// Fused attention (unchanged math from round 2 — mask bits bit-identical).
// ctx now written as bf16 (sole consumer is the bf16 MFMA proj GEMM).
// ---------------------------------------------------------------------------
template <bool MASKED>
__global__ __launch_bounds__(256) void attn_kernel(
    const float* __restrict__ Qf, const float* __restrict__ Kf, const float* __restrict__ Vf,
    const int* __restrict__ ids, unsigned short* __restrict__ ctx, float* __restrict__ colsum)
{
  __shared__ float Qs[64][68];   // Q^T: [d][q]
  __shared__ float KVs[64][68];  // K^T: [d][k] during S; V: [k][d] during PV
  __shared__ float Pt[64][68];   // P^T: [k][q]
  __shared__ float csb[1024];
  __shared__ int   kid[64];
  __shared__ int   qidb[64];

  const int tid = threadIdx.x;
  const int qt = blockIdx.x & 15;
  const int h  = (blockIdx.x >> 4) & 7;
  const int b  = blockIdx.x >> 7;
  const int q0 = qt * 64;
  const int ty = tid >> 5;
  const int tx = tid & 31;
  const size_t bT = (size_t)b * Tz;

  const int sr = tid >> 2;
  const int sd = (tid & 3) << 2;

  {
    const float* qsrc = &Qf[(bT + q0 + sr) * Dz + h * DHz];
#pragma unroll
    for (int i = 0; i < 4; ++i) {
      int d0 = sd + i * 16;
      float4 v = *reinterpret_cast<const float4*>(&qsrc[d0]);
      Qs[d0 + 0][sr] = v.x; Qs[d0 + 1][sr] = v.y; Qs[d0 + 2][sr] = v.z; Qs[d0 + 3][sr] = v.w;
    }
    if (MASKED && tid < 64) qidb[tid] = ids[bT + q0 + tid];
    for (int i = tid; i < 1024; i += 256) csb[i] = 0.f;
  }
  __syncthreads();

  int qidr[8];
  if (MASKED) {
#pragma unroll
    for (int r = 0; r < 8; ++r) qidr[r] = qidb[ty * 8 + r];
  }

  const float* kbase = Kf + (bT + sr) * Dz + h * DHz + sd;
  const float* vbase = Vf + (bT + sr) * Dz + h * DHz + sd;

  // ---------------- pass 1: Z row sums ----------------
  float z[8];
#pragma unroll
  for (int r = 0; r < 8; ++r) z[r] = 0.f;

  float4 kreg[4];
#pragma unroll
  for (int i = 0; i < 4; ++i) kreg[i] = *reinterpret_cast<const float4*>(kbase + i * 16);
  int kidp = (MASKED && tid < 64) ? ids[bT + tid] : 0;

  for (int t = 0; t < 16; ++t) {
#pragma unroll
    for (int i = 0; i < 4; ++i) {
      int d0 = sd + i * 16;
      KVs[d0 + 0][sr] = kreg[i].x; KVs[d0 + 1][sr] = kreg[i].y;
      KVs[d0 + 2][sr] = kreg[i].z; KVs[d0 + 3][sr] = kreg[i].w;
    }
    if (MASKED && tid < 64) kid[tid] = kidp;
    __syncthreads();
    if (t < 15) {
      const float* kb2 = kbase + (size_t)(t + 1) * 64 * Dz;
#pragma unroll
      for (int i = 0; i < 4; ++i) kreg[i] = *reinterpret_cast<const float4*>(kb2 + i * 16);
      if (MASKED && tid < 64) kidp = ids[bT + (t + 1) * 64 + tid];
    }
    float s[8][2];
#pragma unroll
    for (int r = 0; r < 8; ++r) s[r][0] = s[r][1] = 0.f;
#pragma unroll 4
    for (int d = 0; d < 64; ++d) {
      float4 qa = *reinterpret_cast<const float4*>(&Qs[d][ty * 8]);
      float4 qb = *reinterpret_cast<const float4*>(&Qs[d][ty * 8 + 4]);
      float2 kv = *reinterpret_cast<const float2*>(&KVs[d][tx * 2]);
      s[0][0] += qa.x * kv.x; s[0][1] += qa.x * kv.y;
      s[1][0] += qa.y * kv.x; s[1][1] += qa.y * kv.y;
      s[2][0] += qa.z * kv.x; s[2][1] += qa.z * kv.y;
      s[3][0] += qa.w * kv.x; s[3][1] += qa.w * kv.y;
      s[4][0] += qb.x * kv.x; s[4][1] += qb.x * kv.y;
      s[5][0] += qb.y * kv.x; s[5][1] += qb.y * kv.y;
      s[6][0] += qb.z * kv.x; s[6][1] += qb.z * kv.y;
      s[7][0] += qb.w * kv.x; s[7][1] += qb.w * kv.y;
    }
    int ka = 0, kb = 0;
    if (MASKED) { ka = kid[tx * 2]; kb = kid[tx * 2 + 1]; }
#pragma unroll
    for (int r = 0; r < 8; ++r) {
      float e0 = __expf(s[r][0] * 0.125f);
      float e1 = __expf(s[r][1] * 0.125f);
      if (MASKED) {
        if (qidr[r] != ka) e0 = 0.f;
        if (qidr[r] != kb) e1 = 0.f;
      }
      z[r] += e0 + e1;
    }
    __syncthreads();
  }
#pragma unroll
  for (int w = 1; w < 32; w <<= 1) {
#pragma unroll
    for (int r = 0; r < 8; ++r) z[r] += __shfl_xor(z[r], w);
  }
  float invz[8];
#pragma unroll
  for (int r = 0; r < 8; ++r) invz[r] = 1.f / z[r];

  // ---------------- pass 2: P, colsum, PV ----------------
  float o[8][2];
#pragma unroll
  for (int r = 0; r < 8; ++r) o[r][0] = o[r][1] = 0.f;

#pragma unroll
  for (int i = 0; i < 4; ++i) kreg[i] = *reinterpret_cast<const float4*>(kbase + i * 16);
  if (MASKED && tid < 64) kidp = ids[bT + tid];
  float4 vreg[4];

  for (int t = 0; t < 16; ++t) {
#pragma unroll
    for (int i = 0; i < 4; ++i) {
      int d0 = sd + i * 16;
      KVs[d0 + 0][sr] = kreg[i].x; KVs[d0 + 1][sr] = kreg[i].y;
      KVs[d0 + 2][sr] = kreg[i].z; KVs[d0 + 3][sr] = kreg[i].w;
    }
    if (MASKED && tid < 64) kid[tid] = kidp;
    __syncthreads();
    {
      const float* vb2 = vbase + (size_t)t * 64 * Dz;
#pragma unroll
      for (int i = 0; i < 4; ++i) vreg[i] = *reinterpret_cast<const float4*>(vb2 + i * 16);
    }
    float s[8][2];
#pragma unroll
    for (int r = 0; r < 8; ++r) s[r][0] = s[r][1] = 0.f;
#pragma unroll 4
    for (int d = 0; d < 64; ++d) {
      float4 qa = *reinterpret_cast<const float4*>(&Qs[d][ty * 8]);
      float4 qb = *reinterpret_cast<const float4*>(&Qs[d][ty * 8 + 4]);
      float2 kv = *reinterpret_cast<const float2*>(&KVs[d][tx * 2]);
      s[0][0] += qa.x * kv.x; s[0][1] += qa.x * kv.y;
      s[1][0] += qa.y * kv.x; s[1][1] += qa.y * kv.y;
      s[2][0] += qa.z * kv.x; s[2][1] += qa.z * kv.y;
      s[3][0] += qa.w * kv.x; s[3][1] += qa.w * kv.y;
      s[4][0] += qb.x * kv.x; s[4][1] += qb.x * kv.y;
      s[5][0] += qb.y * kv.x; s[5][1] += qb.y * kv.y;
      s[6][0] += qb.z * kv.x; s[6][1] += qb.z * kv.y;
      s[7][0] += qb.w * kv.x; s[7][1] += qb.w * kv.y;
    }
    int ka = 0, kb = 0;
    if (MASKED) { ka = kid[tx * 2]; kb = kid[tx * 2 + 1]; }
    float p[8][2];
#pragma unroll
    for (int r = 0; r < 8; ++r) {
      float e0 = __expf(s[r][0] * 0.125f);
      float e1 = __expf(s[r][1] * 0.125f);
      if (MASKED) {
        if (qidr[r] != ka) e0 = 0.f;
        if (qidr[r] != kb) e1 = 0.f;
      }
      p[r][0] = e0 * invz[r];
      p[r][1] = e1 * invz[r];
    }
    __syncthreads();
#pragma unroll
    for (int i = 0; i < 4; ++i)
      *reinterpret_cast<float4*>(&KVs[sr][sd + i * 16]) = vreg[i];
    float4 w0, w1, w2, w3;
    w0.x = p[0][0]; w0.y = p[1][0]; w0.z = p[2][0]; w0.w = p[3][0];
    w1.x = p[4][0]; w1.y = p[5][0]; w1.z = p[6][0]; w1.w = p[7][0];
    w2.x = p[0][1]; w2.y = p[1][1]; w2.z = p[2][1]; w2.w = p[3][1];
    w3.x = p[4][1]; w3.y = p[5][1]; w3.z = p[6][1]; w3.w = p[7][1];
    *reinterpret_cast<float4*>(&Pt[tx * 2][ty * 8])     = w0;
    *reinterpret_cast<float4*>(&Pt[tx * 2][ty * 8 + 4]) = w1;
    *reinterpret_cast<float4*>(&Pt[tx * 2 + 1][ty * 8])     = w2;
    *reinterpret_cast<float4*>(&Pt[tx * 2 + 1][ty * 8 + 4]) = w3;
    float c0 = p[0][0] + p[1][0] + p[2][0] + p[3][0] + p[4][0] + p[5][0] + p[6][0] + p[7][0];
    float c1 = p[0][1] + p[1][1] + p[2][1] + p[3][1] + p[4][1] + p[5][1] + p[6][1] + p[7][1];
    c0 += __shfl_xor(c0, 32);
    c1 += __shfl_xor(c1, 32);
    if ((tid & 32) == 0) {
      atomicAdd(&csb[t * 64 + tx * 2], c0);
      atomicAdd(&csb[t * 64 + tx * 2 + 1], c1);
    }
    __syncthreads();
    if (t < 15) {
      const float* kb2 = kbase + (size_t)(t + 1) * 64 * Dz;
#pragma unroll
      for (int i = 0; i < 4; ++i) kreg[i] = *reinterpret_cast<const float4*>(kb2 + i * 16);
      if (MASKED && tid < 64) kidp = ids[bT + (t + 1) * 64 + tid];
    }
#pragma unroll 4
    for (int kk = 0; kk < 64; ++kk) {
      float4 pa = *reinterpret_cast<const float4*>(&Pt[kk][ty * 8]);
      float4 pb = *reinterpret_cast<const float4*>(&Pt[kk][ty * 8 + 4]);
      float2 vv = *reinterpret_cast<const float2*>(&KVs[kk][tx * 2]);
      o[0][0] += pa.x * vv.x; o[0][1] += pa.x * vv.y;
      o[1][0] += pa.y * vv.x; o[1][1] += pa.y * vv.y;
      o[2][0] += pa.z * vv.x; o[2][1] += pa.z * vv.y;
      o[3][0] += pa.w * vv.x; o[3][1] += pa.w * vv.y;
      o[4][0] += pb.x * vv.x; o[4][1] += pb.x * vv.y;
      o[5][0] += pb.y * vv.x; o[5][1] += pb.y * vv.y;
      o[6][0] += pb.z * vv.x; o[6][1] += pb.z * vv.y;
      o[7][0] += pb.w * vv.x; o[7][1] += pb.w * vv.y;
    }
    __syncthreads();
  }

  // epilogue: bf16 ctx (consumer = bf16 MFMA proj GEMM) + colsum flush
#pragma unroll
  for (int r = 0; r < 8; ++r) {
    unsigned pk = (unsigned)f2bf(o[r][0]) | ((unsigned)f2bf(o[r][1]) << 16);
    *reinterpret_cast<unsigned*>(&ctx[(bT + q0 + ty * 8 + r) * Dz + h * DHz + tx * 2]) = pk;
  }
  __syncthreads();
#pragma unroll
  for (int i = 0; i < 4; ++i) {
    int k = tid + i * 256;
    atomicAdd(&colsum[bT + k], csb[k] * (1.f / Hz));
  }
}

// ---------------------------------------------------------------------------
// out = LayerNorm(resid + delta); writes fp32 and (optionally) bf16 copy.
// ---------------------------------------------------------------------------
__global__ __launch_bounds__(256) void ln_kernel(const float* __restrict__ resid,
    const float* __restrict__ delta, float* __restrict__ out,
    unsigned short* __restrict__ outbf)
{
  const size_t base = (size_t)blockIdx.x * Dz;
  const int tid = threadIdx.x;
  float x0 = resid[base + tid] + delta[base + tid];
  float x1 = resid[base + tid + 256] + delta[base + tid + 256];
  __shared__ float red[4];
  float s = x0 + x1;
#pragma unroll
  for (int off = 32; off; off >>= 1) s += __shfl_down(s, off);
  if ((tid & 63) == 0) red[tid >> 6] = s;
  __syncthreads();
  const float mean = (red[0] + red[1] + red[2] + red[3]) * (1.f / Dz);
  __syncthreads();
  float d0 = x0 - mean, d1 = x1 - mean;
  float v = d0 * d0 + d1 * d1;
#pragma unroll
  for (int off = 32; off; off >>= 1) v += __shfl_down(v, off);
  if ((tid & 63) == 0) red[tid >> 6] = v;
  __syncthreads();
  const float var = (red[0] + red[1] + red[2] + red[3]) * (1.f / Dz);
  const float rstd = rsqrtf(var + 1e-5f);
  float y0 = d0 * rstd, y1 = d1 * rstd;
  out[base + tid] = y0;
  out[base + tid + 256] = y1;
  if (outbf) {
    outbf[base + tid] = f2bf(y0);
    outbf[base + tid + 256] = f2bf(y1);
  }
}

// ---------------------------------------------------------------------------
// Per batch: min-max normalize colsum, threshold 0.5, run-length window scan.
// ---------------------------------------------------------------------------
__global__ __launch_bounds__(256) void window_ids_kernel(const float* __restrict__ cs,
    int* __restrict__ ids, int* __restrict__ wst, int* __restrict__ nwin)
{
  const int b = blockIdx.x, tid = threadIdx.x;
  __shared__ float vals[Tz];
  __shared__ unsigned char wb[Tz];
  __shared__ int sids[Tz];
  __shared__ float rmin[4], rmax[4];
  float mn = INFINITY, mx = -INFINITY;
  for (int t = tid; t < Tz; t += 256) {
    float v = cs[b * Tz + t];
    vals[t] = v;
    mn = fminf(mn, v); mx = fmaxf(mx, v);
  }
#pragma unroll
  for (int off = 32; off; off >>= 1) {
    mn = fminf(mn, __shfl_down(mn, off));
    mx = fmaxf(mx, __shfl_down(mx, off));
  }
  if ((tid & 63) == 0) { rmin[tid >> 6] = mn; rmax[tid >> 6] = mx; }
  __syncthreads();
  mn = fminf(fminf(rmin[0], rmin[1]), fminf(rmin[2], rmin[3]));
  mx = fmaxf(fmaxf(rmax[0], rmax[1]), fmaxf(rmax[2], rmax[3]));
  const float inv = 1.f / (mx - mn + 1e-8f);
  for (int t = tid; t < Tz; t += 256) wb[t] = (((vals[t] - mn) * inv) >= 0.5f) ? 1 : 0;
  __syncthreads();
  if (tid == 0) {
    int cur = wb[0], start = 0, wid = 0;
    sids[0] = 0;
    wst[b * (Tz + 1)] = 0;
    for (int t = 1; t < Tz; ++t) {
      int wt = wb[t];
      if (wt != cur) {
        cur = wt;
        if (start + 1 != t) {
          start = t;
          ++wid;
          wst[b * (Tz + 1) + wid] = t;
        }
      }
      sids[t] = wid;
    }
    nwin[b] = wid + 1;
    wst[b * (Tz + 1) + wid + 1] = Tz;
  }
  __syncthreads();
  for (int t = tid; t < Tz; t += 256) ids[b * Tz + t] = sids[t];
}

// ---------------------------------------------------------------------------
// wl[b,:] = softmax over keys of layer-2 colsum.
// ---------------------------------------------------------------------------
__global__ __launch_bounds__(256) void wl_softmax_kernel(const float* __restrict__ cs,
                                                         float* __restrict__ wl)
{
  const int b = blockIdx.x, tid = threadIdx.x;
  __shared__ float vals[Tz];
  __shared__ float red[4];
  float mx = -INFINITY;
  for (int t = tid; t < Tz; t += 256) {
    float v = cs[b * Tz + t];
    vals[t] = v;
    mx = fmaxf(mx, v);
  }
#pragma unroll
  for (int off = 32; off; off >>= 1) mx = fmaxf(mx, __shfl_down(mx, off));
  if ((tid & 63) == 0) red[tid >> 6] = mx;
  __syncthreads();
  mx = fmaxf(fmaxf(red[0], red[1]), fmaxf(red[2], red[3]));
  __syncthreads();
  float se = 0.f;
  for (int t = tid; t < Tz; t += 256) {
    float e = expf(vals[t] - mx);
    vals[t] = e;
    se += e;
  }
#pragma unroll
  for (int off = 32; off; off >>= 1) se += __shfl_down(se, off);
  if ((tid & 63) == 0) red[tid >> 6] = se;
  __syncthreads();
  const float inv = 1.f / (red[0] + red[1] + red[2] + red[3]);
  for (int t = tid; t < Tz; t += 256) wl[b * Tz + t] = vals[t] * inv;
}

// ---------------------------------------------------------------------------
// word_tokens rows of output 0.
// ---------------------------------------------------------------------------
__global__ __launch_bounds__(256) void word_tokens_kernel(const float* __restrict__ outl,
    const float* __restrict__ wl, const int* __restrict__ wst, const int* __restrict__ nwin,
    float* __restrict__ out)
{
  const int w = blockIdx.x & (Tz - 1);
  const int b = blockIdx.x >> 10;
  const int tid = threadIdx.x;
  float a0 = 0.f, a1 = 0.f;
  if (w < nwin[b]) {
    const int s = wst[b * (Tz + 1) + w], e = wst[b * (Tz + 1) + w + 1];
    for (int t = s; t < e; ++t) {
      const float sc = wl[b * Tz + t];
      const float* p = &outl[((size_t)(b * Tz + t)) * Dz];
      a0 += p[tid] * sc;
      a1 += p[tid + 256] * sc;
    }
  }
  float* o = &out[((size_t)(b * 2 * Tz + w)) * Dz];
  o[tid] = a0;
  o[tid + 256] = a1;
}

// ---------------------------------------------------------------------------
// out0 rows [T, 2T): copy of the original input x.
// ---------------------------------------------------------------------------
__global__ __launch_bounds__(256) void copy_x_kernel(const float* __restrict__ x,
                                                     float* __restrict__ out)
{
  size_t i = (size_t)blockIdx.x * 256 + threadIdx.x;
  size_t idx = i * 4;
  size_t rowi = idx >> 9;
  size_t d = idx & 511;
  size_t b = rowi >> 10, t = rowi & 1023;
  float4 v = *reinterpret_cast<const float4*>(&x[idx]);
  *reinterpret_cast<float4*>(&out[(((b * 2 * Tz) + Tz + t) << 9) + d]) = v;
}

// ---------------------------------------------------------------------------
// Output 1: window_mapping[b, w, j] = (ids[b,j] == w).
// ---------------------------------------------------------------------------
__global__ __launch_bounds__(256) void winmap_kernel(const int* __restrict__ ids,
                                                     float* __restrict__ out2)
{
  const int w = blockIdx.x & (Tz - 1);
  const int b = blockIdx.x >> 10;
  const int tid = threadIdx.x;
  const int j = tid * 4;
  int4 id4 = *reinterpret_cast<const int4*>(&ids[b * Tz + j]);
  float4 v;
  v.x = (id4.x == w) ? 1.f : 0.f;
  v.y = (id4.y == w) ? 1.f : 0.f;
  v.z = (id4.z == w) ? 1.f : 0.f;
  v.w = (id4.w == w) ? 1.f : 0.f;
  *reinterpret_cast<float4*>(&out2[((size_t)(b * Tz + w)) * Tz + j]) = v;
}

// ---------------------------------------------------------------------------
// Orchestration. Workspace ~129 MB with aggressive aliasing.
// ---------------------------------------------------------------------------
extern "C" void kernel_launch(void* const* d_in, const int* in_sizes, int n_in,
                              void* d_out, int out_size, void* d_ws, size_t ws_size,
                              hipStream_t stream)
{
  (void)in_sizes; (void)n_in; (void)out_size; (void)ws_size;
  const float* x     = (const float*)d_in[0];
  const float* vqkv  = (const float*)d_in[1];
  const float* voutw = (const float*)d_in[2];
  const float* vw1   = (const float*)d_in[3];
  const float* vw2   = (const float*)d_in[4];
  const float* lqkv  = (const float*)d_in[5];
  const float* loutw = (const float*)d_in[6];
  const float* lw1   = (const float*)d_in[7];
  const float* lw2   = (const float*)d_in[8];
  float* out = (float*)d_out;
  float* ws  = (float*)d_ws;

  // fp32 buffers
  float* Q    = ws + 0;         // 4.19M floats  (HIDbf aliases Q+Kb during FFN)
  float* Kb   = ws + 4194304;
  float* Vb   = ws + 8388608;
  float* Y1   = ws + 14680064;
  float* PROJ = ws + 18874368;
  float* OUTV = ws + 23068672;
  float* OUTL = ws + 23068672;  // alias: OUTV dead before OUTL written (L2 ln2)
  // bf16 buffers (ushort)
  unsigned short* SLOT1  = (unsigned short*)(ws + 12582912);  // XBF -> CTXbf(L1) -> CTXbf(L2)
  unsigned short* SLOT2  = (unsigned short*)(ws + 27262976);  // Y1bf(L1) -> OUTVbf -> Y1bf(L2)
  unsigned short* HIDbf  = (unsigned short*)(ws + 0);         // aliases Q+Kb (dead during FFN)
  // bf16 transposed weights
  unsigned short* WVQV = (unsigned short*)(ws + 29360128);              // [512,512]
  unsigned short* WVO  = (unsigned short*)(ws + 29360128 + 131072);     // [512,512]
  unsigned short* WV1  = (unsigned short*)(ws + 29360128 + 262144);     // [2048,512]
  unsigned short* WV2  = (unsigned short*)(ws + 29360128 + 786432);     // [512,2048]
  unsigned short* WLQ0 = (unsigned short*)(ws + 29360128 + 1310720);
  unsigned short* WLQ1 = (unsigned short*)(ws + 29360128 + 1441792);
  unsigned short* WLQ2 = (unsigned short*)(ws + 29360128 + 1572864);
  unsigned short* WLO  = (unsigned short*)(ws + 29360128 + 1703936);
  unsigned short* WL1  = (unsigned short*)(ws + 29360128 + 1835008);    // [2048,512]
  unsigned short* WL2  = (unsigned short*)(ws + 29360128 + 2359296);    // [512,2048]
  // small buffers
  float* CS1  = ws + 32243712;
  float* CS2  = ws + 32251904;
  float* WLs  = ws + 32260096;
  int*   IDS  = (int*)(ws + 32268288);
  int*   WST  = (int*)(ws + 32276480);
  int*   NWIN = (int*)(ws + 32284928);

  dim3 blk(256);
  zero_kernel<<<dim3(64), blk, 0, stream>>>(CS1, 16384);  // CS1+CS2 contiguous

  // weight convert+transpose (fp32 [K,N] -> bf16 [N,K])
  auto wc = [&](const float* in, unsigned short* o, int K, int N) {
    wconv_kernel<<<dim3(N / 32, K / 32), blk, 0, stream>>>(in, o, K, N);
  };
  wc(vqkv + 2 * Dz * Dz, WVQV, Dz, Dz);
  wc(voutw, WVO, Dz, Dz);
  wc(vw1, WV1, Dz, FFz);
  wc(vw2, WV2, FFz, Dz);
  wc(lqkv + 0 * Dz * Dz, WLQ0, Dz, Dz);
  wc(lqkv + 1 * Dz * Dz, WLQ1, Dz, Dz);
  wc(lqkv + 2 * Dz * Dz, WLQ2, Dz, Dz);
  wc(loutw, WLO, Dz, Dz);
  wc(lw1, WL1, Dz, FFz);
  wc(lw2, WL2, FFz, Dz);
  fconv_kernel<<<dim3(Mz * Dz / 1024), blk, 0, stream>>>(x, SLOT1, Mz * Dz / 4);  // x -> bf16

  auto mgemm = [&](const unsigned short* A, const unsigned short* BT, float* Cf,
                   unsigned short* Cbf, int K, int N, int relu) {
    mfma_gemm_kernel<<<dim3(N / 64, Mz / 64), dim3(64), 0, stream>>>(A, BT, Cf, Cbf, K, N, relu);
  };
  auto fgemm = [&](const float* A, const float* Bm, float* C, int N, int K) {
    gemm_kernel<<<dim3(N / 128, Mz / 128), blk, 0, stream>>>(A, Bm, C, Mz, N, K);
  };

  // ---------------- layer 1 (vanilla) ----------------
  fgemm(x, vqkv + 0 * Dz * Dz, Q, Dz, Dz);   // fp32: mask bits depend on Q,K
  fgemm(x, vqkv + 1 * Dz * Dz, Kb, Dz, Dz);
  mgemm(SLOT1, WVQV, Vb, nullptr, Dz, Dz, 0);                 // V (bf16-safe)
  attn_kernel<false><<<dim3(Bz * Hz * (Tz / 64)), blk, 0, stream>>>(Q, Kb, Vb, nullptr, SLOT1, CS1);
  mgemm(SLOT1, WVO, PROJ, nullptr, Dz, Dz, 0);                // proj
  ln_kernel<<<dim3(Mz), blk, 0, stream>>>(x, PROJ, Y1, SLOT2);
  mgemm(SLOT2, WV1, nullptr, HIDbf, Dz, FFz, 1);              // FFN1 + ReLU -> bf16
  mgemm(HIDbf, WV2, PROJ, nullptr, FFz, Dz, 0);               // FFN2
  ln_kernel<<<dim3(Mz), blk, 0, stream>>>(Y1, PROJ, OUTV, SLOT2);

  // ---------------- dynamic window generation ----------------
  window_ids_kernel<<<dim3(Bz), blk, 0, stream>>>(CS1, IDS, WST, NWIN);

  // ---------------- layer 2 (block-diagonal window mask) ----------------
  mgemm(SLOT2, WLQ0, Q, nullptr, Dz, Dz, 0);
  mgemm(SLOT2, WLQ1, Kb, nullptr, Dz, Dz, 0);
  mgemm(SLOT2, WLQ2, Vb, nullptr, Dz, Dz, 0);
  attn_kernel<true><<<dim3(Bz * Hz * (Tz / 64)), blk, 0, stream>>>(Q, Kb, Vb, IDS, SLOT1, CS2);
  mgemm(SLOT1, WLO, PROJ, nullptr, Dz, Dz, 0);
  ln_kernel<<<dim3(Mz), blk, 0, stream>>>(OUTV, PROJ, Y1, SLOT2);
  mgemm(SLOT2, WL1, nullptr, HIDbf, Dz, FFz, 1);
  mgemm(HIDbf, WL2, PROJ, nullptr, FFz, Dz, 0);
  ln_kernel<<<dim3(Mz), blk, 0, stream>>>(Y1, PROJ, OUTL, nullptr);

  // ---------------- pooling + outputs ----------------
  wl_softmax_kernel<<<dim3(Bz), blk, 0, stream>>>(CS2, WLs);
  word_tokens_kernel<<<dim3(Bz * Tz), blk, 0, stream>>>(OUTL, WLs, WST, NWIN, out);
  copy_x_kernel<<<dim3(Bz * Tz * Dz / 1024), blk, 0, stream>>>(x, out);
  winmap_kernel<<<dim3(Bz * Tz), blk, 0, stream>>>(IDS, out + (size_t)Bz * 2 * Tz * Dz);
}

// Round 6
// 1318.911 us; speedup vs baseline: 2.5306x; 1.2452x over previous
//
#include <hip/hip_runtime.h>
#include <math.h>

// Problem constants (fixed by setup_inputs)
#define Bz 8
#define Tz 1024
#define Dz 512
#define FFz 2048
#define Hz 8
#define DHz 64
#define Mz (Bz * Tz)  // 8192 rows

typedef __attribute__((ext_vector_type(8))) short short8;   // 8 bf16 (4 VGPRs)
typedef __attribute__((ext_vector_type(4))) float f32x4;    // MFMA accumulator

__device__ inline unsigned short f2bf(float f) {  // RNE fp32 -> bf16
  unsigned u = __builtin_bit_cast(unsigned, f);
  return (unsigned short)((u + 0x7FFFu + ((u >> 16) & 1u)) >> 16);
}
__device__ inline float bf2f(unsigned short h) {
  unsigned u = (unsigned)h << 16;
  return __builtin_bit_cast(float, u);
}

// ---------------------------------------------------------------------------
// zero fill (colsum accumulators must start at 0; ws is poisoned 0xAA)
// ---------------------------------------------------------------------------
__global__ __launch_bounds__(256) void zero_kernel(float* __restrict__ p, int n) {
  int i = blockIdx.x * 256 + threadIdx.x;
  if (i < n) p[i] = 0.f;
}

// ---------------------------------------------------------------------------
// Weight convert+transpose: fp32 [K,N] -> bf16 [N,K] (MFMA B-frag layout).
// ---------------------------------------------------------------------------
__global__ __launch_bounds__(256) void wconv_kernel(const float* __restrict__ in,
    unsigned short* __restrict__ out, int K, int N)
{
  __shared__ float t[32][33];
  const int bn = blockIdx.x * 32, bk = blockIdx.y * 32;
  const int tx = threadIdx.x & 31, ty = threadIdx.x >> 5;
#pragma unroll
  for (int i = 0; i < 32; i += 8) t[ty + i][tx] = in[(size_t)(bk + ty + i) * N + bn + tx];
  __syncthreads();
#pragma unroll
  for (int i = 0; i < 32; i += 8)
    out[(size_t)(bn + ty + i) * K + bk + tx] = f2bf(t[tx][ty + i]);
}

// ---------------------------------------------------------------------------
// Flat fp32 -> bf16 convert (for x).
// ---------------------------------------------------------------------------
__global__ __launch_bounds__(256) void fconv_kernel(const float* __restrict__ in,
    unsigned short* __restrict__ out, int n4)
{
  int i = blockIdx.x * 256 + threadIdx.x;
  if (i >= n4) return;
  float4 v = *reinterpret_cast<const float4*>(&in[(size_t)i * 4]);
  ushort4 o;
  o.x = f2bf(v.x); o.y = f2bf(v.y); o.z = f2bf(v.z); o.w = f2bf(v.w);
  *reinterpret_cast<ushort4*>(&out[(size_t)i * 4]) = o;
}

// ---------------------------------------------------------------------------
// bf16 MFMA GEMM, 64x64 tile per wave, direct-from-global fragments.
// Epilogue modes: 0 fp32 C | 1 bf16 C | 2 bf16 C + ReLU
//               | 4 V^T layout: p1[((b*H+h)*64+d)*T + t] bf16 (N must be 512)
// ---------------------------------------------------------------------------
__global__ __launch_bounds__(64) void mfma_gemm_kernel(
    const unsigned short* __restrict__ A, const unsigned short* __restrict__ BT,
    void* __restrict__ p1, int K, int N, int mode)
{
  const int l = threadIdx.x;
  const int m0 = blockIdx.y * 64;
  const int n0 = blockIdx.x * 64;
  const int mr = l & 15, quad = l >> 4;

  f32x4 acc[4][4];
  const f32x4 zero = {0.f, 0.f, 0.f, 0.f};
#pragma unroll
  for (int i = 0; i < 4; ++i)
#pragma unroll
    for (int j = 0; j < 4; ++j) acc[i][j] = zero;

  const unsigned short* Ap = A + (size_t)(m0 + mr) * K + quad * 8;
  const unsigned short* Bp = BT + (size_t)(n0 + mr) * K + quad * 8;

  short8 a[4], b[4], an[4], bn[4];
#pragma unroll
  for (int i = 0; i < 4; ++i) {
    a[i] = *reinterpret_cast<const short8*>(Ap + (size_t)i * 16 * K);
    b[i] = *reinterpret_cast<const short8*>(Bp + (size_t)i * 16 * K);
  }
  for (int k0 = 0; k0 < K; k0 += 32) {
    if (k0 + 32 < K) {
#pragma unroll
      for (int i = 0; i < 4; ++i) {
        an[i] = *reinterpret_cast<const short8*>(Ap + (size_t)i * 16 * K + k0 + 32);
        bn[i] = *reinterpret_cast<const short8*>(Bp + (size_t)i * 16 * K + k0 + 32);
      }
    }
#pragma unroll
    for (int i = 0; i < 4; ++i)
#pragma unroll
      for (int j = 0; j < 4; ++j)
        acc[i][j] = __builtin_amdgcn_mfma_f32_16x16x32_bf16(a[i], b[j], acc[i][j], 0, 0, 0);
#pragma unroll
    for (int i = 0; i < 4; ++i) { a[i] = an[i]; b[i] = bn[i]; }
  }

  // C/D layout: col = lane&15, row = quad*4 + reg   [measured: m89/m91]
  if (mode == 4) {  // V^T: 4 consecutive tokens same feature -> ushort4
    unsigned short* Vt = (unsigned short*)p1;
#pragma unroll
    for (int i = 0; i < 4; ++i)
#pragma unroll
      for (int j = 0; j < 4; ++j) {
        const int col = n0 + j * 16 + mr;        // feature: h = col>>6, d = col&63
        const int row0 = m0 + i * 16 + quad * 4; // token base (4 consecutive)
        const int bb = row0 >> 10, t0 = row0 & 1023;
        ushort4 pk;
        pk.x = f2bf(acc[i][j][0]); pk.y = f2bf(acc[i][j][1]);
        pk.z = f2bf(acc[i][j][2]); pk.w = f2bf(acc[i][j][3]);
        *reinterpret_cast<ushort4*>(
            &Vt[((size_t)((bb * Hz + (col >> 6)) * DHz + (col & 63))) * Tz + t0]) = pk;
      }
  } else if (mode == 0) {
    float* Cf = (float*)p1;
#pragma unroll
    for (int i = 0; i < 4; ++i)
#pragma unroll
      for (int j = 0; j < 4; ++j) {
        const int col = n0 + j * 16 + mr;
#pragma unroll
        for (int rr = 0; rr < 4; ++rr)
          Cf[(size_t)(m0 + i * 16 + quad * 4 + rr) * N + col] = acc[i][j][rr];
      }
  } else {
    unsigned short* C = (unsigned short*)p1;
    const bool relu = (mode == 2);
#pragma unroll
    for (int i = 0; i < 4; ++i)
#pragma unroll
      for (int j = 0; j < 4; ++j) {
        const int col = n0 + j * 16 + mr;
#pragma unroll
        for (int rr = 0; rr < 4; ++rr) {
          float v = acc[i][j][rr];
          if (relu) v = fmaxf(v, 0.f);
          C[(size_t)(m0 + i * 16 + quad * 4 + rr) * N + col] = f2bf(v);
        }
      }
  }
}

// ---------------------------------------------------------------------------
// fp32 VALU GEMM for layer-1 Q,K (mask-critical path — accumulation is
// bit-identical to round 3's passing kernel). Writes fp32 C (for the fp32
// colsum kernel) and a bf16 copy (for the MFMA ctx kernel).
// ---------------------------------------------------------------------------
__global__ __launch_bounds__(256) void gemm_qk_kernel(
    const float* __restrict__ A, const float* __restrict__ Bm,
    float* __restrict__ Cf, unsigned short* __restrict__ Cbf,
    int M, int N, int K)
{
  __shared__ float As[16][132];
  __shared__ float Bs[16][132];
  const int tid = threadIdx.x;
  const int bm = blockIdx.y * 128;
  const int bn = blockIdx.x * 128;
  const int tx = tid & 15, ty = tid >> 4;
  float acc[8][8];
#pragma unroll
  for (int i = 0; i < 8; ++i)
#pragma unroll
    for (int j = 0; j < 8; ++j) acc[i][j] = 0.f;

  for (int k0 = 0; k0 < K; k0 += 16) {
#pragma unroll
    for (int i = 0; i < 2; ++i) {
      int idx = tid + i * 256;
      int r = idx >> 2, kv = (idx & 3) << 2;
      float4 a = *reinterpret_cast<const float4*>(&A[(size_t)(bm + r) * K + k0 + kv]);
      As[kv + 0][r] = a.x; As[kv + 1][r] = a.y; As[kv + 2][r] = a.z; As[kv + 3][r] = a.w;
      int kk = idx >> 5, nv = (idx & 31) << 2;
      *reinterpret_cast<float4*>(&Bs[kk][nv]) =
          *reinterpret_cast<const float4*>(&Bm[(size_t)(k0 + kk) * N + bn + nv]);
    }
    __syncthreads();
#pragma unroll
    for (int kk = 0; kk < 16; ++kk) {
      float ar[8], br[8];
#pragma unroll
      for (int i = 0; i < 8; ++i) ar[i] = As[kk][ty * 8 + i];
#pragma unroll
      for (int j = 0; j < 4; ++j) {
        br[j]     = Bs[kk][tx * 4 + j];
        br[4 + j] = Bs[kk][64 + tx * 4 + j];
      }
#pragma unroll
      for (int i = 0; i < 8; ++i)
#pragma unroll
        for (int j = 0; j < 8; ++j) acc[i][j] += ar[i] * br[j];
    }
    __syncthreads();
  }
#pragma unroll
  for (int i = 0; i < 8; ++i) {
    size_t row = (size_t)(bm + ty * 8 + i);
    float4 v0, v1;
    v0.x = acc[i][0]; v0.y = acc[i][1]; v0.z = acc[i][2]; v0.w = acc[i][3];
    v1.x = acc[i][4]; v1.y = acc[i][5]; v1.z = acc[i][6]; v1.w = acc[i][7];
    *reinterpret_cast<float4*>(&Cf[row * N + bn + tx * 4]) = v0;
    *reinterpret_cast<float4*>(&Cf[row * N + bn + 64 + tx * 4]) = v1;
    ushort4 h0, h1;
    h0.x = f2bf(v0.x); h0.y = f2bf(v0.y); h0.z = f2bf(v0.z); h0.w = f2bf(v0.w);
    h1.x = f2bf(v1.x); h1.y = f2bf(v1.y); h1.z = f2bf(v1.z); h1.w = f2bf(v1.w);
    *reinterpret_cast<ushort4*>(&Cbf[row * N + bn + tx * 4]) = h0;
    *reinterpret_cast<ushort4*>(&Cbf[row * N + bn + 64 + tx * 4]) = h1;
  }
}

// ---------------------------------------------------------------------------
// Layer-1 colsum, fp32 VALU — S/exp/z/colsum arithmetic VERBATIM from the
// round-3 attention kernel (which passed, incl. graph replays): same LDS
// tiling, same micro-kernel statement order, same reductions. This is the
// ONLY producer of the window-mask bits. Also stores invz per (b,h,q) for
// the MFMA ctx kernel.
// ---------------------------------------------------------------------------
__global__ __launch_bounds__(256) void colsum_f32_kernel(
    const float* __restrict__ Qf, const float* __restrict__ Kf,
    float* __restrict__ colsum, float* __restrict__ invzG)
{
  __shared__ float Qs[64][68];   // Q^T: [d][q]
  __shared__ float KVs[64][68];  // K^T: [d][k]
  __shared__ float csb[1024];

  const int tid = threadIdx.x;
  const int qt = blockIdx.x & 15;
  const int h  = (blockIdx.x >> 4) & 7;
  const int b  = blockIdx.x >> 7;
  const int q0 = qt * 64;
  const int ty = tid >> 5;
  const int tx = tid & 31;
  const size_t bT = (size_t)b * Tz;

  const int sr = tid >> 2;
  const int sd = (tid & 3) << 2;

  {
    const float* qsrc = &Qf[(bT + q0 + sr) * Dz + h * DHz];
#pragma unroll
    for (int i = 0; i < 4; ++i) {
      int d0 = sd + i * 16;
      float4 v = *reinterpret_cast<const float4*>(&qsrc[d0]);
      Qs[d0 + 0][sr] = v.x; Qs[d0 + 1][sr] = v.y; Qs[d0 + 2][sr] = v.z; Qs[d0 + 3][sr] = v.w;
    }
    for (int i = tid; i < 1024; i += 256) csb[i] = 0.f;
  }
  __syncthreads();

  const float* kbase = Kf + (bT + sr) * Dz + h * DHz + sd;

  // ---------------- pass 1: Z row sums ----------------
  float z[8];
#pragma unroll
  for (int r = 0; r < 8; ++r) z[r] = 0.f;

  float4 kreg[4];
#pragma unroll
  for (int i = 0; i < 4; ++i) kreg[i] = *reinterpret_cast<const float4*>(kbase + i * 16);

  for (int t = 0; t < 16; ++t) {
#pragma unroll
    for (int i = 0; i < 4; ++i) {
      int d0 = sd + i * 16;
      KVs[d0 + 0][sr] = kreg[i].x; KVs[d0 + 1][sr] = kreg[i].y;
      KVs[d0 + 2][sr] = kreg[i].z; KVs[d0 + 3][sr] = kreg[i].w;
    }
    __syncthreads();
    if (t < 15) {
      const float* kb2 = kbase + (size_t)(t + 1) * 64 * Dz;
#pragma unroll
      for (int i = 0; i < 4; ++i) kreg[i] = *reinterpret_cast<const float4*>(kb2 + i * 16);
    }
    float s[8][2];
#pragma unroll
    for (int r = 0; r < 8; ++r) s[r][0] = s[r][1] = 0.f;
#pragma unroll 4
    for (int d = 0; d < 64; ++d) {
      float4 qa = *reinterpret_cast<const float4*>(&Qs[d][ty * 8]);
      float4 qb = *reinterpret_cast<const float4*>(&Qs[d][ty * 8 + 4]);
      float2 kv = *reinterpret_cast<const float2*>(&KVs[d][tx * 2]);
      s[0][0] += qa.x * kv.x; s[0][1] += qa.x * kv.y;
      s[1][0] += qa.y * kv.x; s[1][1] += qa.y * kv.y;
      s[2][0] += qa.z * kv.x; s[2][1] += qa.z * kv.y;
      s[3][0] += qa.w * kv.x; s[3][1] += qa.w * kv.y;
      s[4][0] += qb.x * kv.x; s[4][1] += qb.x * kv.y;
      s[5][0] += qb.y * kv.x; s[5][1] += qb.y * kv.y;
      s[6][0] += qb.z * kv.x; s[6][1] += qb.z * kv.y;
      s[7][0] += qb.w * kv.x; s[7][1] += qb.w * kv.y;
    }
#pragma unroll
    for (int r = 0; r < 8; ++r) {
      float e0 = __expf(s[r][0] * 0.125f);
      float e1 = __expf(s[r][1] * 0.125f);
      z[r] += e0 + e1;
    }
    __syncthreads();
  }
#pragma unroll
  for (int w = 1; w < 32; w <<= 1) {
#pragma unroll
    for (int r = 0; r < 8; ++r) z[r] += __shfl_xor(z[r], w);
  }
  float invz[8];
#pragma unroll
  for (int r = 0; r < 8; ++r) invz[r] = 1.f / z[r];
  if (tx == 0) {
#pragma unroll
    for (int r = 0; r < 8; ++r)
      invzG[(size_t)(b * Hz + h) * Tz + q0 + ty * 8 + r] = invz[r];
  }

  // ---------------- pass 2: P colsum ----------------
#pragma unroll
  for (int i = 0; i < 4; ++i) kreg[i] = *reinterpret_cast<const float4*>(kbase + i * 16);

  for (int t = 0; t < 16; ++t) {
#pragma unroll
    for (int i = 0; i < 4; ++i) {
      int d0 = sd + i * 16;
      KVs[d0 + 0][sr] = kreg[i].x; KVs[d0 + 1][sr] = kreg[i].y;
      KVs[d0 + 2][sr] = kreg[i].z; KVs[d0 + 3][sr] = kreg[i].w;
    }
    __syncthreads();
    float s[8][2];
#pragma unroll
    for (int r = 0; r < 8; ++r) s[r][0] = s[r][1] = 0.f;
#pragma unroll 4
    for (int d = 0; d < 64; ++d) {
      float4 qa = *reinterpret_cast<const float4*>(&Qs[d][ty * 8]);
      float4 qb = *reinterpret_cast<const float4*>(&Qs[d][ty * 8 + 4]);
      float2 kv = *reinterpret_cast<const float2*>(&KVs[d][tx * 2]);
      s[0][0] += qa.x * kv.x; s[0][1] += qa.x * kv.y;
      s[1][0] += qa.y * kv.x; s[1][1] += qa.y * kv.y;
      s[2][0] += qa.z * kv.x; s[2][1] += qa.z * kv.y;
      s[3][0] += qa.w * kv.x; s[3][1] += qa.w * kv.y;
      s[4][0] += qb.x * kv.x; s[4][1] += qb.x * kv.y;
      s[5][0] += qb.y * kv.x; s[5][1] += qb.y * kv.y;
      s[6][0] += qb.z * kv.x; s[6][1] += qb.z * kv.y;
      s[7][0] += qb.w * kv.x; s[7][1] += qb.w * kv.y;
    }
    float p[8][2];
#pragma unroll
    for (int r = 0; r < 8; ++r) {
      float e0 = __expf(s[r][0] * 0.125f);
      float e1 = __expf(s[r][1] * 0.125f);
      p[r][0] = e0 * invz[r];
      p[r][1] = e1 * invz[r];
    }
    float c0 = p[0][0] + p[1][0] + p[2][0] + p[3][0] + p[4][0] + p[5][0] + p[6][0] + p[7][0];
    float c1 = p[0][1] + p[1][1] + p[2][1] + p[3][1] + p[4][1] + p[5][1] + p[6][1] + p[7][1];
    c0 += __shfl_xor(c0, 32);
    c1 += __shfl_xor(c1, 32);
    if ((tid & 32) == 0) {
      atomicAdd(&csb[t * 64 + tx * 2], c0);
      atomicAdd(&csb[t * 64 + tx * 2 + 1], c1);
    }
    __syncthreads();
    if (t < 15) {
      const float* kb2 = kbase + (size_t)(t + 1) * 64 * Dz;
#pragma unroll
      for (int i = 0; i < 4; ++i) kreg[i] = *reinterpret_cast<const float4*>(kb2 + i * 16);
    }
  }
  __syncthreads();
#pragma unroll
  for (int i = 0; i < 4; ++i) {
    int k = tid + i * 256;
    atomicAdd(&colsum[bT + k], csb[k] * (1.f / Hz));
  }
}

// ---------------------------------------------------------------------------
// Layer-1 ctx via MFMA, SINGLE pass: S = bf16 QK^T (error-tolerant — ctx
// feeds only continuous paths), P = exp(s)/z with z from colsum_f32_kernel.
// One block = (b,h,64-q tile); wave owns 16 q rows; Pld rows wave-private
// (no barriers). V pre-transposed (Vt).
// ---------------------------------------------------------------------------
__global__ __launch_bounds__(256) void attn_ctx_kernel(
    const unsigned short* __restrict__ Qb, const unsigned short* __restrict__ Kb,
    const unsigned short* __restrict__ Vt, const float* __restrict__ invzG,
    unsigned short* __restrict__ ctx)
{
  __shared__ unsigned short Pld[64][76];
  const int tid = threadIdx.x;
  const int lane = tid & 63, wave = tid >> 6;
  const int c = lane & 15, quad = lane >> 4;
  const int qt = blockIdx.x & 15;
  const int h  = (blockIdx.x >> 4) & 7;
  const int b  = blockIdx.x >> 7;
  const size_t bT = (size_t)b * Tz;
  const int qrow = qt * 64 + wave * 16;
  const int hoff = h * DHz;

  const size_t qbase = (bT + qrow + c) * Dz + hoff + quad * 8;
  short8 q0 = *reinterpret_cast<const short8*>(Qb + qbase);
  short8 q1 = *reinterpret_cast<const short8*>(Qb + qbase + 32);

  float invz[4];
#pragma unroll
  for (int rr = 0; rr < 4; ++rr)
    invz[rr] = invzG[(size_t)(b * Hz + h) * Tz + qrow + quad * 4 + rr];

  const f32x4 zf = {0.f, 0.f, 0.f, 0.f};
  f32x4 ot[4] = {zf, zf, zf, zf};

  for (int t = 0; t < 16; ++t) {
    const int k0 = t * 64;
#pragma unroll
    for (int sub = 0; sub < 4; ++sub) {
      const size_t kb = (bT + k0 + sub * 16 + c) * Dz + hoff + quad * 8;
      short8 kh0 = *reinterpret_cast<const short8*>(Kb + kb);
      short8 kh1 = *reinterpret_cast<const short8*>(Kb + kb + 32);
      f32x4 acc = zf;
      acc = __builtin_amdgcn_mfma_f32_16x16x32_bf16(q0, kh0, acc, 0, 0, 0);
      acc = __builtin_amdgcn_mfma_f32_16x16x32_bf16(q1, kh1, acc, 0, 0, 0);
#pragma unroll
      for (int rr = 0; rr < 4; ++rr) {
        float p = __expf(acc[rr] * 0.125f) * invz[rr];
        Pld[(wave << 4) + quad * 4 + rr][sub * 16 + c] = f2bf(p);
      }
    }
    union { short8 v; ushort4 hh[2]; } pb0, pb1;
    pb0.hh[0] = *reinterpret_cast<const ushort4*>(&Pld[(wave << 4) + c][quad * 8]);
    pb0.hh[1] = *reinterpret_cast<const ushort4*>(&Pld[(wave << 4) + c][quad * 8 + 4]);
    pb1.hh[0] = *reinterpret_cast<const ushort4*>(&Pld[(wave << 4) + c][32 + quad * 8]);
    pb1.hh[1] = *reinterpret_cast<const ushort4*>(&Pld[(wave << 4) + c][32 + quad * 8 + 4]);
#pragma unroll
    for (int ds = 0; ds < 4; ++ds) {
      const size_t va = ((size_t)((b * Hz + h) * DHz + ds * 16 + c)) * Tz + k0 + quad * 8;
      short8 v0 = *reinterpret_cast<const short8*>(Vt + va);
      short8 v1 = *reinterpret_cast<const short8*>(Vt + va + 32);
      ot[ds] = __builtin_amdgcn_mfma_f32_16x16x32_bf16(v0, pb0.v, ot[ds], 0, 0, 0);
      ot[ds] = __builtin_amdgcn_mfma_f32_16x16x32_bf16(v1, pb1.v, ot[ds], 0, 0, 0);
    }
  }

  const size_t cb = (bT + qrow + c) * Dz + hoff;
#pragma unroll
  for (int ds = 0; ds < 4; ++ds) {
    ushort4 pk;
    pk.x = f2bf(ot[ds][0]); pk.y = f2bf(ot[ds][1]);
    pk.z = f2bf(ot[ds][2]); pk.w = f2bf(ot[ds][3]);
    *reinterpret_cast<ushort4*>(&ctx[cb + ds * 16 + quad * 4]) = pk;
  }
}

// ---------------------------------------------------------------------------
// Layer-2 MFMA attention (masked, bf16 scores — colsum feeds only the wl
// softmax, no thresholds). Two passes (z, then P/colsum/PV).
// ---------------------------------------------------------------------------
__global__ __launch_bounds__(256) void attn_mfma2_kernel(
    const unsigned short* __restrict__ Qh, const unsigned short* __restrict__ Kh,
    const unsigned short* __restrict__ Vt, const int* __restrict__ ids,
    unsigned short* __restrict__ ctx, float* __restrict__ colsum)
{
  __shared__ unsigned short Pld[64][76];
  __shared__ float csb[1024];

  const int tid = threadIdx.x;
  const int lane = tid & 63, wave = tid >> 6;
  const int c = lane & 15, quad = lane >> 4;
  const int qt = blockIdx.x & 15;
  const int h  = (blockIdx.x >> 4) & 7;
  const int b  = blockIdx.x >> 7;
  const size_t bT = (size_t)b * Tz;
  const int qrow = qt * 64 + wave * 16;
  const int hoff = h * DHz;

  for (int i = tid; i < 1024; i += 256) csb[i] = 0.f;

  const size_t qbase = (bT + qrow + c) * Dz + hoff + quad * 8;
  short8 q0 = *reinterpret_cast<const short8*>(Qh + qbase);
  short8 q1 = *reinterpret_cast<const short8*>(Qh + qbase + 32);

  int qid[4];
#pragma unroll
  for (int rr = 0; rr < 4; ++rr) qid[rr] = ids[bT + qrow + quad * 4 + rr];
  __syncthreads();  // csb zeros visible before pass-2 atomics

  const f32x4 zf = {0.f, 0.f, 0.f, 0.f};

  // pass 1: z
  float z[4] = {0.f, 0.f, 0.f, 0.f};
  for (int t = 0; t < 16; ++t) {
    const int k0 = t * 64;
#pragma unroll
    for (int sub = 0; sub < 4; ++sub) {
      const size_t kb = (bT + k0 + sub * 16 + c) * Dz + hoff + quad * 8;
      short8 kh0 = *reinterpret_cast<const short8*>(Kh + kb);
      short8 kh1 = *reinterpret_cast<const short8*>(Kh + kb + 32);
      f32x4 acc = zf;
      acc = __builtin_amdgcn_mfma_f32_16x16x32_bf16(q0, kh0, acc, 0, 0, 0);
      acc = __builtin_amdgcn_mfma_f32_16x16x32_bf16(q1, kh1, acc, 0, 0, 0);
      int kidv = ids[bT + k0 + sub * 16 + c];
#pragma unroll
      for (int rr = 0; rr < 4; ++rr) {
        float e = __expf(acc[rr] * 0.125f);
        if (qid[rr] != kidv) e = 0.f;
        z[rr] += e;
      }
    }
  }
#pragma unroll
  for (int w = 1; w < 16; w <<= 1) {
#pragma unroll
    for (int rr = 0; rr < 4; ++rr) z[rr] += __shfl_xor(z[rr], w);
  }
  float invz[4];
#pragma unroll
  for (int rr = 0; rr < 4; ++rr) invz[rr] = 1.f / z[rr];

  // pass 2: P, colsum, PV
  f32x4 ot[4] = {zf, zf, zf, zf};
  for (int t = 0; t < 16; ++t) {
    const int k0 = t * 64;
#pragma unroll
    for (int sub = 0; sub < 4; ++sub) {
      const size_t kb = (bT + k0 + sub * 16 + c) * Dz + hoff + quad * 8;
      short8 kh0 = *reinterpret_cast<const short8*>(Kh + kb);
      short8 kh1 = *reinterpret_cast<const short8*>(Kh + kb + 32);
      f32x4 acc = zf;
      acc = __builtin_amdgcn_mfma_f32_16x16x32_bf16(q0, kh0, acc, 0, 0, 0);
      acc = __builtin_amdgcn_mfma_f32_16x16x32_bf16(q1, kh1, acc, 0, 0, 0);
      int kidv = ids[bT + k0 + sub * 16 + c];
      float p[4];
#pragma unroll
      for (int rr = 0; rr < 4; ++rr) {
        float e = __expf(acc[rr] * 0.125f);
        if (qid[rr] != kidv) e = 0.f;
        p[rr] = e * invz[rr];
      }
      float cs = p[0] + p[1] + p[2] + p[3];
      cs += __shfl_xor(cs, 16);
      cs += __shfl_xor(cs, 32);
      if (quad == 0) atomicAdd(&csb[k0 + sub * 16 + c], cs);
#pragma unroll
      for (int rr = 0; rr < 4; ++rr)
        Pld[(wave << 4) + quad * 4 + rr][sub * 16 + c] = f2bf(p[rr]);
    }
    union { short8 v; ushort4 hh[2]; } pb0, pb1;
    pb0.hh[0] = *reinterpret_cast<const ushort4*>(&Pld[(wave << 4) + c][quad * 8]);
    pb0.hh[1] = *reinterpret_cast<const ushort4*>(&Pld[(wave << 4) + c][quad * 8 + 4]);
    pb1.hh[0] = *reinterpret_cast<const ushort4*>(&Pld[(wave << 4) + c][32 + quad * 8]);
    pb1.hh[1] = *reinterpret_cast<const ushort4*>(&Pld[(wave << 4) + c][32 + quad * 8 + 4]);
#pragma unroll
    for (int ds = 0; ds < 4; ++ds) {
      const size_t va = ((size_t)((b * Hz + h) * DHz + ds * 16 + c)) * Tz + k0 + quad * 8;
      short8 v0 = *reinterpret_cast<const short8*>(Vt + va);
      short8 v1 = *reinterpret_cast<const short8*>(Vt + va + 32);
      ot[ds] = __builtin_amdgcn_mfma_f32_16x16x32_bf16(v0, pb0.v, ot[ds], 0, 0, 0);
      ot[ds] = __builtin_amdgcn_mfma_f32_16x16x32_bf16(v1, pb1.v, ot[ds], 0, 0, 0);
    }
  }

  const size_t cb = (bT + qrow + c) * Dz + hoff;
#pragma unroll
  for (int ds = 0; ds < 4; ++ds) {
    ushort4 pk;
    pk.x = f2bf(ot[ds][0]); pk.y = f2bf(ot[ds][1]);
    pk.z = f2bf(ot[ds][2]); pk.w = f2bf(ot[ds][3]);
    *reinterpret_cast<ushort4*>(&ctx[cb + ds * 16 + quad * 4]) = pk;
  }
  __syncthreads();
  for (int i = tid; i < 1024; i += 256)
    atomicAdd(&colsum[bT + i], csb[i] * (1.f / Hz));
}

// ---------------------------------------------------------------------------
// out = LayerNorm(resid + delta). resid fp32 (residf) if non-null else bf16.
// ---------------------------------------------------------------------------
__global__ __launch_bounds__(256) void ln_kernel(const float* __restrict__ residf,
    const unsigned short* __restrict__ residbf, const float* __restrict__ delta,
    float* __restrict__ outf, unsigned short* __restrict__ outbf)
{
  const size_t base = (size_t)blockIdx.x * Dz;
  const int tid = threadIdx.x;
  float r0, r1;
  if (residf) {
    r0 = residf[base + tid]; r1 = residf[base + tid + 256];
  } else {
    r0 = bf2f(residbf[base + tid]); r1 = bf2f(residbf[base + tid + 256]);
  }
  float x0 = r0 + delta[base + tid];
  float x1 = r1 + delta[base + tid + 256];
  __shared__ float red[4];
  float s = x0 + x1;
#pragma unroll
  for (int off = 32; off; off >>= 1) s += __shfl_down(s, off);
  if ((tid & 63) == 0) red[tid >> 6] = s;
  __syncthreads();
  const float mean = (red[0] + red[1] + red[2] + red[3]) * (1.f / Dz);
  __syncthreads();
  float d0 = x0 - mean, d1 = x1 - mean;
  float v = d0 * d0 + d1 * d1;
#pragma unroll
  for (int off = 32; off; off >>= 1) v += __shfl_down(v, off);
  if ((tid & 63) == 0) red[tid >> 6] = v;
  __syncthreads();
  const float var = (red[0] + red[1] + red[2] + red[3]) * (1.f / Dz);
  const float rstd = rsqrtf(var + 1e-5f);
  float y0 = d0 * rstd, y1 = d1 * rstd;
  if (outf) {
    outf[base + tid] = y0;
    outf[base + tid + 256] = y1;
  }
  outbf[base + tid] = f2bf(y0);
  outbf[base + tid + 256] = f2bf(y1);
}

// ---------------------------------------------------------------------------
// Per batch: min-max normalize colsum, threshold 0.5, run-length window scan.
// ---------------------------------------------------------------------------
__global__ __launch_bounds__(256) void window_ids_kernel(const float* __restrict__ cs,
    int* __restrict__ ids, int* __restrict__ wst, int* __restrict__ nwin)
{
  const int b = blockIdx.x, tid = threadIdx.x;
  __shared__ float vals[Tz];
  __shared__ unsigned char wb[Tz];
  __shared__ int sids[Tz];
  __shared__ float rmin[4], rmax[4];
  float mn = INFINITY, mx = -INFINITY;
  for (int t = tid; t < Tz; t += 256) {
    float v = cs[b * Tz + t];
    vals[t] = v;
    mn = fminf(mn, v); mx = fmaxf(mx, v);
  }
#pragma unroll
  for (int off = 32; off; off >>= 1) {
    mn = fminf(mn, __shfl_down(mn, off));
    mx = fmaxf(mx, __shfl_down(mx, off));
  }
  if ((tid & 63) == 0) { rmin[tid >> 6] = mn; rmax[tid >> 6] = mx; }
  __syncthreads();
  mn = fminf(fminf(rmin[0], rmin[1]), fminf(rmin[2], rmin[3]));
  mx = fmaxf(fmaxf(rmax[0], rmax[1]), fmaxf(rmax[2], rmax[3]));
  const float inv = 1.f / (mx - mn + 1e-8f);
  for (int t = tid; t < Tz; t += 256) wb[t] = (((vals[t] - mn) * inv) >= 0.5f) ? 1 : 0;
  __syncthreads();
  if (tid == 0) {
    int cur = wb[0], start = 0, wid = 0;
    sids[0] = 0;
    wst[b * (Tz + 1)] = 0;
    for (int t = 1; t < Tz; ++t) {
      int wt = wb[t];
      if (wt != cur) {
        cur = wt;
        if (start + 1 != t) {
          start = t;
          ++wid;
          wst[b * (Tz + 1) + wid] = t;
        }
      }
      sids[t] = wid;
    }
    nwin[b] = wid + 1;
    wst[b * (Tz + 1) + wid + 1] = Tz;
  }
  __syncthreads();
  for (int t = tid; t < Tz; t += 256) ids[b * Tz + t] = sids[t];
}

// ---------------------------------------------------------------------------
// wl[b,:] = softmax over keys of layer-2 colsum.
// ---------------------------------------------------------------------------
__global__ __launch_bounds__(256) void wl_softmax_kernel(const float* __restrict__ cs,
                                                         float* __restrict__ wl)
{
  const int b = blockIdx.x, tid = threadIdx.x;
  __shared__ float vals[Tz];
  __shared__ float red[4];
  float mx = -INFINITY;
  for (int t = tid; t < Tz; t += 256) {
    float v = cs[b * Tz + t];
    vals[t] = v;
    mx = fmaxf(mx, v);
  }
#pragma unroll
  for (int off = 32; off; off >>= 1) mx = fmaxf(mx, __shfl_down(mx, off));
  if ((tid & 63) == 0) red[tid >> 6] = mx;
  __syncthreads();
  mx = fmaxf(fmaxf(red[0], red[1]), fmaxf(red[2], red[3]));
  __syncthreads();
  float se = 0.f;
  for (int t = tid; t < Tz; t += 256) {
    float e = expf(vals[t] - mx);
    vals[t] = e;
    se += e;
  }
#pragma unroll
  for (int off = 32; off; off >>= 1) se += __shfl_down(se, off);
  if ((tid & 63) == 0) red[tid >> 6] = se;
  __syncthreads();
  const float inv = 1.f / (red[0] + red[1] + red[2] + red[3]);
  for (int t = tid; t < Tz; t += 256) wl[b * Tz + t] = vals[t] * inv;
}

// ---------------------------------------------------------------------------
// word_tokens rows of output 0 (outl bf16).
// ---------------------------------------------------------------------------
__global__ __launch_bounds__(256) void word_tokens_kernel(
    const unsigned short* __restrict__ outl, const float* __restrict__ wl,
    const int* __restrict__ wst, const int* __restrict__ nwin, float* __restrict__ out)
{
  const int w = blockIdx.x & (Tz - 1);
  const int b = blockIdx.x >> 10;
  const int tid = threadIdx.x;
  float a0 = 0.f, a1 = 0.f;
  if (w < nwin[b]) {
    const int s = wst[b * (Tz + 1) + w], e = wst[b * (Tz + 1) + w + 1];
    for (int t = s; t < e; ++t) {
      const float sc = wl[b * Tz + t];
      const unsigned short* p = &outl[((size_t)(b * Tz + t)) * Dz];
      a0 += bf2f(p[tid]) * sc;
      a1 += bf2f(p[tid + 256]) * sc;
    }
  }
  float* o = &out[((size_t)(b * 2 * Tz + w)) * Dz];
  o[tid] = a0;
  o[tid + 256] = a1;
}

// ---------------------------------------------------------------------------
// out0 rows [T, 2T): copy of the original input x.
// ---------------------------------------------------------------------------
__global__ __launch_bounds__(256) void copy_x_kernel(const float* __restrict__ x,
                                                     float* __restrict__ out)
{
  size_t i = (size_t)blockIdx.x * 256 + threadIdx.x;
  size_t idx = i * 4;
  size_t rowi = idx >> 9;
  size_t d = idx & 511;
  size_t b = rowi >> 10, t = rowi & 1023;
  float4 v = *reinterpret_cast<const float4*>(&x[idx]);
  *reinterpret_cast<float4*>(&out[(((b * 2 * Tz) + Tz + t) << 9) + d]) = v;
}

// ---------------------------------------------------------------------------
// Output 1: window_mapping[b, w, j] = (ids[b,j] == w).
// ---------------------------------------------------------------------------
__global__ __launch_bounds__(256) void winmap_kernel(const int* __restrict__ ids,
                                                     float* __restrict__ out2)
{
  const int w = blockIdx.x & (Tz - 1);
  const int b = blockIdx.x >> 10;
  const int tid = threadIdx.x;
  const int j = tid * 4;
  int4 id4 = *reinterpret_cast<const int4*>(&ids[b * Tz + j]);
  float4 v;
  v.x = (id4.x == w) ? 1.f : 0.f;
  v.y = (id4.y == w) ? 1.f : 0.f;
  v.z = (id4.z == w) ? 1.f : 0.f;
  v.w = (id4.w == w) ? 1.f : 0.f;
  *reinterpret_cast<float4*>(&out2[((size_t)(b * Tz + w)) * Tz + j]) = v;
}

// ---------------------------------------------------------------------------
// Orchestration. Workspace ~121 MB (PROJ aliases Qf, Y1 aliases Kf,
// XBF aliases HIDbf).
// ---------------------------------------------------------------------------
extern "C" void kernel_launch(void* const* d_in, const int* in_sizes, int n_in,
                              void* d_out, int out_size, void* d_ws, size_t ws_size,
                              hipStream_t stream)
{
  (void)in_sizes; (void)n_in; (void)out_size; (void)ws_size;
  const float* x     = (const float*)d_in[0];
  const float* vqkv  = (const float*)d_in[1];
  const float* voutw = (const float*)d_in[2];
  const float* vw1   = (const float*)d_in[3];
  const float* vw2   = (const float*)d_in[4];
  const float* lqkv  = (const float*)d_in[5];
  const float* loutw = (const float*)d_in[6];
  const float* lw1   = (const float*)d_in[7];
  const float* lw2   = (const float*)d_in[8];
  float* out = (float*)d_out;
  float* ws  = (float*)d_ws;

  float* Qf = ws + 0;           // fp32 Q (L1), dead after colsum -> PROJ
  float* Kf = ws + 4194304;     // fp32 K (L1), dead after colsum -> Y1
  float* PROJ = ws + 0;         // alias Qf
  float* Y1   = ws + 4194304;   // alias Kf
  unsigned short* QHbf = (unsigned short*)(ws + 8388608);   // bf16 Q (L1+L2)
  unsigned short* KHbf = (unsigned short*)(ws + 10485760);  // bf16 K (L1+L2)
  unsigned short* VT   = (unsigned short*)(ws + 12582912);
  unsigned short* SLOT1 = (unsigned short*)(ws + 14680064); // attn ctx bf16
  unsigned short* SLOT2 = (unsigned short*)(ws + 16777216); // LN bf16 out
  unsigned short* HIDbf = (unsigned short*)(ws + 18874368); // FFN hidden
  unsigned short* XBF   = (unsigned short*)(ws + 18874368); // alias (pre-FFN)
  // bf16 transposed weights
  unsigned short* WVQV = (unsigned short*)(ws + 27262976);
  unsigned short* WVO  = (unsigned short*)(ws + 27394048);
  unsigned short* WV1  = (unsigned short*)(ws + 27525120);
  unsigned short* WV2  = (unsigned short*)(ws + 28049408);
  unsigned short* WLQ0 = (unsigned short*)(ws + 28573696);
  unsigned short* WLQ1 = (unsigned short*)(ws + 28704768);
  unsigned short* WLQ2 = (unsigned short*)(ws + 28835840);
  unsigned short* WLO  = (unsigned short*)(ws + 28966912);
  unsigned short* WL1  = (unsigned short*)(ws + 29097984);
  unsigned short* WL2  = (unsigned short*)(ws + 29622272);
  // small buffers
  float* CS1   = ws + 30146560;
  float* CS2   = ws + 30154752;
  float* WLs   = ws + 30162944;
  int*   IDS   = (int*)(ws + 30171136);
  int*   WST   = (int*)(ws + 30179328);
  int*   NWIN  = (int*)(ws + 30187776);
  float* INVZ  = ws + 30195968;  // (B*H*T) = 65536 floats

  dim3 blk(256);
  zero_kernel<<<dim3(64), blk, 0, stream>>>(CS1, 16384);  // CS1+CS2 contiguous

  auto wc = [&](const float* in, unsigned short* o, int K, int N) {
    wconv_kernel<<<dim3(N / 32, K / 32), blk, 0, stream>>>(in, o, K, N);
  };
  wc(vqkv + 2 * Dz * Dz, WVQV, Dz, Dz);
  wc(voutw, WVO, Dz, Dz);
  wc(vw1, WV1, Dz, FFz);
  wc(vw2, WV2, FFz, Dz);
  wc(lqkv + 0 * Dz * Dz, WLQ0, Dz, Dz);
  wc(lqkv + 1 * Dz * Dz, WLQ1, Dz, Dz);
  wc(lqkv + 2 * Dz * Dz, WLQ2, Dz, Dz);
  wc(loutw, WLO, Dz, Dz);
  wc(lw1, WL1, Dz, FFz);
  wc(lw2, WL2, FFz, Dz);
  fconv_kernel<<<dim3(Mz * Dz / 1024), blk, 0, stream>>>(x, XBF, Mz * Dz / 4);

  auto mgemm = [&](const unsigned short* A, const unsigned short* BT, void* p1,
                   int K, int N, int mode) {
    mfma_gemm_kernel<<<dim3(N / 64, Mz / 64), dim3(64), 0, stream>>>(A, BT, p1, K, N, mode);
  };

  // ---------------- layer 1 (vanilla) ----------------
  gemm_qk_kernel<<<dim3(4, 64), blk, 0, stream>>>(x, vqkv + 0 * Dz * Dz, Qf, QHbf, Mz, Dz, Dz);
  gemm_qk_kernel<<<dim3(4, 64), blk, 0, stream>>>(x, vqkv + 1 * Dz * Dz, Kf, KHbf, Mz, Dz, Dz);
  colsum_f32_kernel<<<dim3(Bz * Hz * 16), blk, 0, stream>>>(Qf, Kf, CS1, INVZ);  // mask path
  window_ids_kernel<<<dim3(Bz), blk, 0, stream>>>(CS1, IDS, WST, NWIN);
  mgemm(XBF, WVQV, VT, Dz, Dz, 4);                          // V -> V^T bf16
  attn_ctx_kernel<<<dim3(Bz * Hz * 16), blk, 0, stream>>>(QHbf, KHbf, VT, INVZ, SLOT1);
  mgemm(SLOT1, WVO, PROJ, Dz, Dz, 0);                       // proj (Qf dead)
  ln_kernel<<<dim3(Mz), blk, 0, stream>>>(x, nullptr, PROJ, Y1, SLOT2);
  mgemm(SLOT2, WV1, HIDbf, Dz, FFz, 2);                     // FFN1 + ReLU
  mgemm(HIDbf, WV2, PROJ, FFz, Dz, 0);                      // FFN2
  ln_kernel<<<dim3(Mz), blk, 0, stream>>>(Y1, nullptr, PROJ, nullptr, SLOT2);

  // ---------------- layer 2 (block-diagonal window mask) ----------------
  mgemm(SLOT2, WLQ0, QHbf, Dz, Dz, 1);
  mgemm(SLOT2, WLQ1, KHbf, Dz, Dz, 1);
  mgemm(SLOT2, WLQ2, VT, Dz, Dz, 4);
  attn_mfma2_kernel<<<dim3(Bz * Hz * 16), blk, 0, stream>>>(QHbf, KHbf, VT, IDS, SLOT1, CS2);
  mgemm(SLOT1, WLO, PROJ, Dz, Dz, 0);
  ln_kernel<<<dim3(Mz), blk, 0, stream>>>(nullptr, SLOT2, PROJ, Y1, SLOT2);
  mgemm(SLOT2, WL1, HIDbf, Dz, FFz, 2);
  mgemm(HIDbf, WL2, PROJ, FFz, Dz, 0);
  ln_kernel<<<dim3(Mz), blk, 0, stream>>>(Y1, nullptr, PROJ, nullptr, SLOT2);

  // ---------------- pooling + outputs ----------------
  wl_softmax_kernel<<<dim3(Bz), blk, 0, stream>>>(CS2, WLs);
  word_tokens_kernel<<<dim3(Bz * Tz), blk, 0, stream>>>(SLOT2, WLs, WST, NWIN, out);
  copy_x_kernel<<<dim3(Bz * Tz * Dz / 1024), blk, 0, stream>>>(x, out);
  winmap_kernel<<<dim3(Bz * Tz), blk, 0, stream>>>(IDS, out + (size_t)Bz * 2 * Tz * Dz);
}

// Round 8
// 1116.494 us; speedup vs baseline: 2.9894x; 1.1813x over previous
//
#include <hip/hip_runtime.h>
#include <math.h>

// Problem constants (fixed by setup_inputs)
#define Bz 8
#define Tz 1024
#define Dz 512
#define FFz 2048
#define Hz 8
#define DHz 64
#define Mz (Bz * Tz)  // 8192 rows

typedef __attribute__((ext_vector_type(8))) short short8;   // 8 bf16 (4 VGPRs)
typedef __attribute__((ext_vector_type(4))) float f32x4;    // MFMA accumulator

__device__ inline unsigned short f2bf(float f) {  // RNE fp32 -> bf16
  unsigned u = __builtin_bit_cast(unsigned, f);
  return (unsigned short)((u + 0x7FFFu + ((u >> 16) & 1u)) >> 16);
}
__device__ inline float bf2f(unsigned short h) {
  unsigned u = (unsigned)h << 16;
  return __builtin_bit_cast(float, u);
}

// ---------------------------------------------------------------------------
// Fused prep: 10 weight convert+transposes (fp32 [K,N] -> bf16 [N,K]) +
// colsum zero-fill + x -> bf16.
// ---------------------------------------------------------------------------
struct WDesc { const float* src; unsigned short* dst; int K; int N; int blk0; };
struct PrepArgs { WDesc d[10]; int nwc; };

__global__ __launch_bounds__(256) void prep_kernel(PrepArgs P,
    const float* __restrict__ x, unsigned short* __restrict__ xbf,
    float* __restrict__ csz)
{
  const int bid = blockIdx.x;
  const int tid = threadIdx.x;
  if (bid < P.nwc) {  // wconv slice
    int i = 0;
    while (i < 9 && bid >= P.d[i + 1].blk0) ++i;
    const WDesc w = P.d[i];
    const int lb = bid - w.blk0;
    const int nbn = w.N / 32;
    const int bn = (lb % nbn) * 32, bk = (lb / nbn) * 32;
    __shared__ float t[32][33];
    const int tx = tid & 31, ty = tid >> 5;
#pragma unroll
    for (int r = 0; r < 32; r += 8)
      t[ty + r][tx] = w.src[(size_t)(bk + ty + r) * w.N + bn + tx];
    __syncthreads();
#pragma unroll
    for (int r = 0; r < 32; r += 8)
      w.dst[(size_t)(bn + ty + r) * w.K + bk + tx] = f2bf(t[tx][ty + r]);
  } else if (bid < P.nwc + 64) {  // zero slice (CS1+CS2 = 16384 floats)
    int idx = (bid - P.nwc) * 256 + tid;
    csz[idx] = 0.f;
  } else {  // fconv slice: 4096 blocks, 4 floats/thread
    int i = (bid - P.nwc - 64) * 256 + tid;
    float4 v = *reinterpret_cast<const float4*>(&x[(size_t)i * 4]);
    ushort4 o;
    o.x = f2bf(v.x); o.y = f2bf(v.y); o.z = f2bf(v.z); o.w = f2bf(v.w);
    *reinterpret_cast<ushort4*>(&xbf[(size_t)i * 4]) = o;
  }
}

// ---------------------------------------------------------------------------
// bf16 MFMA GEMM, 64x64 tile per wave, direct-from-global fragments.
// Epilogue modes: 0 fp32 C | 1 bf16 C | 2 bf16 C + ReLU
//   | 4 V^T layout: p1[((b*H+h)*64+d)*T + t] bf16 (N must be 512)
//   | 5 merged QKV (N=1536): cols 0-511 -> p1 bf16, 512-1023 -> p2,
//     1024-1535 -> p3 in V^T layout.
// ---------------------------------------------------------------------------
__global__ __launch_bounds__(64) void mfma_gemm_kernel(
    const unsigned short* __restrict__ A, const unsigned short* __restrict__ BT,
    void* __restrict__ p1, void* __restrict__ p2, void* __restrict__ p3,
    int K, int N, int mode)
{
  const int l = threadIdx.x;
  const int m0 = blockIdx.y * 64;
  const int n0 = blockIdx.x * 64;
  const int mr = l & 15, quad = l >> 4;

  f32x4 acc[4][4];
  const f32x4 zero = {0.f, 0.f, 0.f, 0.f};
#pragma unroll
  for (int i = 0; i < 4; ++i)
#pragma unroll
    for (int j = 0; j < 4; ++j) acc[i][j] = zero;

  const unsigned short* Ap = A + (size_t)(m0 + mr) * K + quad * 8;
  const unsigned short* Bp = BT + (size_t)(n0 + mr) * K + quad * 8;

  short8 a[4], b[4], an[4], bn[4];
#pragma unroll
  for (int i = 0; i < 4; ++i) {
    a[i] = *reinterpret_cast<const short8*>(Ap + (size_t)i * 16 * K);
    b[i] = *reinterpret_cast<const short8*>(Bp + (size_t)i * 16 * K);
  }
  for (int k0 = 0; k0 < K; k0 += 32) {
    if (k0 + 32 < K) {
#pragma unroll
      for (int i = 0; i < 4; ++i) {
        an[i] = *reinterpret_cast<const short8*>(Ap + (size_t)i * 16 * K + k0 + 32);
        bn[i] = *reinterpret_cast<const short8*>(Bp + (size_t)i * 16 * K + k0 + 32);
      }
    }
#pragma unroll
    for (int i = 0; i < 4; ++i)
#pragma unroll
      for (int j = 0; j < 4; ++j)
        acc[i][j] = __builtin_amdgcn_mfma_f32_16x16x32_bf16(a[i], b[j], acc[i][j], 0, 0, 0);
#pragma unroll
    for (int i = 0; i < 4; ++i) { a[i] = an[i]; b[i] = bn[i]; }
  }

  // C/D layout: col = lane&15, row = quad*4 + reg   [measured: m89/m91]
  int emode = mode;
  unsigned short* Cbf = (unsigned short*)p1;
  unsigned short* Vt  = (unsigned short*)p1;
  int ncol = N, coff = 0;
  if (mode == 5) {  // uniform per block: n0 is a multiple of 64
    if (n0 < 512)       { emode = 1; Cbf = (unsigned short*)p1; ncol = 512; coff = 0; }
    else if (n0 < 1024) { emode = 1; Cbf = (unsigned short*)p2; ncol = 512; coff = 512; }
    else                { emode = 4; Vt = (unsigned short*)p3; coff = 1024; }
  }
  if (emode == 4) {  // V^T: 4 consecutive tokens same feature -> ushort4
#pragma unroll
    for (int i = 0; i < 4; ++i)
#pragma unroll
      for (int j = 0; j < 4; ++j) {
        const int col = n0 - coff + j * 16 + mr;  // feature: h = col>>6, d = col&63
        const int row0 = m0 + i * 16 + quad * 4;  // token base (4 consecutive)
        const int bb = row0 >> 10, t0 = row0 & 1023;
        ushort4 pk;
        pk.x = f2bf(acc[i][j][0]); pk.y = f2bf(acc[i][j][1]);
        pk.z = f2bf(acc[i][j][2]); pk.w = f2bf(acc[i][j][3]);
        *reinterpret_cast<ushort4*>(
            &Vt[((size_t)((bb * Hz + (col >> 6)) * DHz + (col & 63))) * Tz + t0]) = pk;
      }
  } else if (emode == 0) {
    float* Cf = (float*)p1;
#pragma unroll
    for (int i = 0; i < 4; ++i)
#pragma unroll
      for (int j = 0; j < 4; ++j) {
        const int col = n0 + j * 16 + mr;
#pragma unroll
        for (int rr = 0; rr < 4; ++rr)
          Cf[(size_t)(m0 + i * 16 + quad * 4 + rr) * N + col] = acc[i][j][rr];
      }
  } else {
    const bool relu = (emode == 2);
#pragma unroll
    for (int i = 0; i < 4; ++i)
#pragma unroll
      for (int j = 0; j < 4; ++j) {
        const int col = n0 - coff + j * 16 + mr;
#pragma unroll
        for (int rr = 0; rr < 4; ++rr) {
          float v = acc[i][j][rr];
          if (relu) v = fmaxf(v, 0.f);
          Cbf[(size_t)(m0 + i * 16 + quad * 4 + rr) * ncol + col] = f2bf(v);
        }
      }
  }
}

// ---------------------------------------------------------------------------
// fp32 VALU GEMM for layer-1 Q AND K in one dispatch (per-thread arithmetic
// identical to rounds 3/6 -> mask inputs bit-identical).
// ---------------------------------------------------------------------------
__global__ __launch_bounds__(256) void gemm_qk_kernel(
    const float* __restrict__ A, const float* __restrict__ vqkv,
    float* __restrict__ Qf, unsigned short* __restrict__ Qbf,
    float* __restrict__ Kf, unsigned short* __restrict__ Kbf, int N, int K)
{
  __shared__ float As[16][132];
  __shared__ float Bs[16][132];
  const int tid = threadIdx.x;
  const int sel = blockIdx.y >> 6;
  const int bm = (blockIdx.y & 63) * 128;
  const int bn = blockIdx.x * 128;
  const float* Bm = vqkv + (size_t)sel * Dz * Dz;
  float* Cf = sel ? Kf : Qf;
  unsigned short* Cbf = sel ? Kbf : Qbf;
  const int tx = tid & 15, ty = tid >> 4;
  float acc[8][8];
#pragma unroll
  for (int i = 0; i < 8; ++i)
#pragma unroll
    for (int j = 0; j < 8; ++j) acc[i][j] = 0.f;

  for (int k0 = 0; k0 < K; k0 += 16) {
#pragma unroll
    for (int i = 0; i < 2; ++i) {
      int idx = tid + i * 256;
      int r = idx >> 2, kv = (idx & 3) << 2;
      float4 a = *reinterpret_cast<const float4*>(&A[(size_t)(bm + r) * K + k0 + kv]);
      As[kv + 0][r] = a.x; As[kv + 1][r] = a.y; As[kv + 2][r] = a.z; As[kv + 3][r] = a.w;
      int kk = idx >> 5, nv = (idx & 31) << 2;
      *reinterpret_cast<float4*>(&Bs[kk][nv]) =
          *reinterpret_cast<const float4*>(&Bm[(size_t)(k0 + kk) * N + bn + nv]);
    }
    __syncthreads();
#pragma unroll
    for (int kk = 0; kk < 16; ++kk) {
      float ar[8], br[8];
#pragma unroll
      for (int i = 0; i < 8; ++i) ar[i] = As[kk][ty * 8 + i];
#pragma unroll
      for (int j = 0; j < 4; ++j) {
        br[j]     = Bs[kk][tx * 4 + j];
        br[4 + j] = Bs[kk][64 + tx * 4 + j];
      }
#pragma unroll
      for (int i = 0; i < 8; ++i)
#pragma unroll
        for (int j = 0; j < 8; ++j) acc[i][j] += ar[i] * br[j];
    }
    __syncthreads();
  }
#pragma unroll
  for (int i = 0; i < 8; ++i) {
    size_t row = (size_t)(bm + ty * 8 + i);
    float4 v0, v1;
    v0.x = acc[i][0]; v0.y = acc[i][1]; v0.z = acc[i][2]; v0.w = acc[i][3];
    v1.x = acc[i][4]; v1.y = acc[i][5]; v1.z = acc[i][6]; v1.w = acc[i][7];
    *reinterpret_cast<float4*>(&Cf[row * N + bn + tx * 4]) = v0;
    *reinterpret_cast<float4*>(&Cf[row * N + bn + 64 + tx * 4]) = v1;
    ushort4 h0, h1;
    h0.x = f2bf(v0.x); h0.y = f2bf(v0.y); h0.z = f2bf(v0.z); h0.w = f2bf(v0.w);
    h1.x = f2bf(v1.x); h1.y = f2bf(v1.y); h1.z = f2bf(v1.z); h1.w = f2bf(v1.w);
    *reinterpret_cast<ushort4*>(&Cbf[row * N + bn + tx * 4]) = h0;
    *reinterpret_cast<ushort4*>(&Cbf[row * N + bn + 64 + tx * 4]) = h1;
  }
}

// ---------------------------------------------------------------------------
// Layer-1 colsum, fp32 VALU — per-thread S/exp/z arithmetic VERBATIM from
// round 3/6 (passing). DETERMINISTIC reduction: NO atomics anywhere —
// xor32 fold (fixed shfl order) -> single-writer CSP[wave][key] LDS slots ->
// fixed-order combine -> non-atomic per-block PART write. A separate reduce
// kernel sums block partials in fixed order. Run-to-run bits are identical.
// ---------------------------------------------------------------------------
__global__ __launch_bounds__(256) void colsum_f32_kernel(
    const float* __restrict__ Qf, const float* __restrict__ Kf,
    float* __restrict__ part, float* __restrict__ invzG)
{
  __shared__ float Qs[64][68];   // Q^T: [d][q]
  __shared__ float KVs[64][68];  // K^T: [d][k]
  __shared__ float CSP[4][1024]; // per-wave colsum partials (single writer)

  const int tid = threadIdx.x;
  const int qt = blockIdx.x & 15;
  const int h  = (blockIdx.x >> 4) & 7;
  const int b  = blockIdx.x >> 7;
  const int q0 = qt * 64;
  const int ty = tid >> 5;
  const int tx = tid & 31;
  const size_t bT = (size_t)b * Tz;

  const int sr = tid >> 2;
  const int sd = (tid & 3) << 2;

  {
    const float* qsrc = &Qf[(bT + q0 + sr) * Dz + h * DHz];
#pragma unroll
    for (int i = 0; i < 4; ++i) {
      int d0 = sd + i * 16;
      float4 v = *reinterpret_cast<const float4*>(&qsrc[d0]);
      Qs[d0 + 0][sr] = v.x; Qs[d0 + 1][sr] = v.y; Qs[d0 + 2][sr] = v.z; Qs[d0 + 3][sr] = v.w;
    }
  }
  __syncthreads();

  const float* kbase = Kf + (bT + sr) * Dz + h * DHz + sd;

  // ---------------- pass 1: Z row sums ----------------
  float z[8];
#pragma unroll
  for (int r = 0; r < 8; ++r) z[r] = 0.f;

  float4 kreg[4];
#pragma unroll
  for (int i = 0; i < 4; ++i) kreg[i] = *reinterpret_cast<const float4*>(kbase + i * 16);

  for (int t = 0; t < 16; ++t) {
#pragma unroll
    for (int i = 0; i < 4; ++i) {
      int d0 = sd + i * 16;
      KVs[d0 + 0][sr] = kreg[i].x; KVs[d0 + 1][sr] = kreg[i].y;
      KVs[d0 + 2][sr] = kreg[i].z; KVs[d0 + 3][sr] = kreg[i].w;
    }
    __syncthreads();
    if (t < 15) {
      const float* kb2 = kbase + (size_t)(t + 1) * 64 * Dz;
#pragma unroll
      for (int i = 0; i < 4; ++i) kreg[i] = *reinterpret_cast<const float4*>(kb2 + i * 16);
    }
    float s[8][2];
#pragma unroll
    for (int r = 0; r < 8; ++r) s[r][0] = s[r][1] = 0.f;
#pragma unroll 4
    for (int d = 0; d < 64; ++d) {
      float4 qa = *reinterpret_cast<const float4*>(&Qs[d][ty * 8]);
      float4 qb = *reinterpret_cast<const float4*>(&Qs[d][ty * 8 + 4]);
      float2 kv = *reinterpret_cast<const float2*>(&KVs[d][tx * 2]);
      s[0][0] += qa.x * kv.x; s[0][1] += qa.x * kv.y;
      s[1][0] += qa.y * kv.x; s[1][1] += qa.y * kv.y;
      s[2][0] += qa.z * kv.x; s[2][1] += qa.z * kv.y;
      s[3][0] += qa.w * kv.x; s[3][1] += qa.w * kv.y;
      s[4][0] += qb.x * kv.x; s[4][1] += qb.x * kv.y;
      s[5][0] += qb.y * kv.x; s[5][1] += qb.y * kv.y;
      s[6][0] += qb.z * kv.x; s[6][1] += qb.z * kv.y;
      s[7][0] += qb.w * kv.x; s[7][1] += qb.w * kv.y;
    }
#pragma unroll
    for (int r = 0; r < 8; ++r) {
      float e0 = __expf(s[r][0] * 0.125f);
      float e1 = __expf(s[r][1] * 0.125f);
      z[r] += e0 + e1;
    }
    __syncthreads();
  }
#pragma unroll
  for (int w = 1; w < 32; w <<= 1) {
#pragma unroll
    for (int r = 0; r < 8; ++r) z[r] += __shfl_xor(z[r], w);
  }
  float invz[8];
#pragma unroll
  for (int r = 0; r < 8; ++r) invz[r] = 1.f / z[r];
  if (tx == 0) {
#pragma unroll
    for (int r = 0; r < 8; ++r)
      invzG[(size_t)(b * Hz + h) * Tz + q0 + ty * 8 + r] = invz[r];
  }

  // ---------------- pass 2: P colsum (deterministic) ----------------
#pragma unroll
  for (int i = 0; i < 4; ++i) kreg[i] = *reinterpret_cast<const float4*>(kbase + i * 16);

  for (int t = 0; t < 16; ++t) {
#pragma unroll
    for (int i = 0; i < 4; ++i) {
      int d0 = sd + i * 16;
      KVs[d0 + 0][sr] = kreg[i].x; KVs[d0 + 1][sr] = kreg[i].y;
      KVs[d0 + 2][sr] = kreg[i].z; KVs[d0 + 3][sr] = kreg[i].w;
    }
    __syncthreads();
    float s[8][2];
#pragma unroll
    for (int r = 0; r < 8; ++r) s[r][0] = s[r][1] = 0.f;
#pragma unroll 4
    for (int d = 0; d < 64; ++d) {
      float4 qa = *reinterpret_cast<const float4*>(&Qs[d][ty * 8]);
      float4 qb = *reinterpret_cast<const float4*>(&Qs[d][ty * 8 + 4]);
      float2 kv = *reinterpret_cast<const float2*>(&KVs[d][tx * 2]);
      s[0][0] += qa.x * kv.x; s[0][1] += qa.x * kv.y;
      s[1][0] += qa.y * kv.x; s[1][1] += qa.y * kv.y;
      s[2][0] += qa.z * kv.x; s[2][1] += qa.z * kv.y;
      s[3][0] += qa.w * kv.x; s[3][1] += qa.w * kv.y;
      s[4][0] += qb.x * kv.x; s[4][1] += qb.x * kv.y;
      s[5][0] += qb.y * kv.x; s[5][1] += qb.y * kv.y;
      s[6][0] += qb.z * kv.x; s[6][1] += qb.z * kv.y;
      s[7][0] += qb.w * kv.x; s[7][1] += qb.w * kv.y;
    }
    float p[8][2];
#pragma unroll
    for (int r = 0; r < 8; ++r) {
      float e0 = __expf(s[r][0] * 0.125f);
      float e1 = __expf(s[r][1] * 0.125f);
      p[r][0] = e0 * invz[r];
      p[r][1] = e1 * invz[r];
    }
    float c0 = p[0][0] + p[1][0] + p[2][0] + p[3][0] + p[4][0] + p[5][0] + p[6][0] + p[7][0];
    float c1 = p[0][1] + p[1][1] + p[2][1] + p[3][1] + p[4][1] + p[5][1] + p[6][1] + p[7][1];
    c0 += __shfl_xor(c0, 32);
    c1 += __shfl_xor(c1, 32);
    if ((tid & 32) == 0) {  // single writer per (wave, key): no race, no atomic
      CSP[tid >> 6][t * 64 + tx * 2] = c0;
      CSP[tid >> 6][t * 64 + tx * 2 + 1] = c1;
    }
    __syncthreads();
    if (t < 15) {
      const float* kb2 = kbase + (size_t)(t + 1) * 64 * Dz;
#pragma unroll
      for (int i = 0; i < 4; ++i) kreg[i] = *reinterpret_cast<const float4*>(kb2 + i * 16);
    }
  }
  __syncthreads();
  // fixed-order combine + non-atomic block-partial write
#pragma unroll
  for (int i = 0; i < 4; ++i) {
    int k = tid + i * 256;
    float v = ((CSP[0][k] + CSP[1][k]) + CSP[2][k]) + CSP[3][k];
    part[(size_t)blockIdx.x * 1024 + k] = v * (1.f / Hz);
  }
}

// ---------------------------------------------------------------------------
// Deterministic colsum reduce: CS1[b,key] = sum over the 128 (h,qt) block
// partials in fixed ascending order. One thread per output.
// ---------------------------------------------------------------------------
__global__ __launch_bounds__(256) void colsum_reduce_kernel(
    const float* __restrict__ part, float* __restrict__ colsum)
{
  const int i = blockIdx.x * 256 + threadIdx.x;  // 0..8191
  const int b = i >> 10, k = i & 1023;
  const float* p = part + (size_t)(b * 128) * 1024 + k;
  float s = 0.f;
  for (int j = 0; j < 128; ++j) s += p[(size_t)j * 1024];
  colsum[i] = s;
}

// ---------------------------------------------------------------------------
// Layer-1 ctx via MFMA, SINGLE pass (z from colsum kernel). bf16 S is
// error-tolerant: ctx feeds only continuous paths.
// ---------------------------------------------------------------------------
__global__ __launch_bounds__(256) void attn_ctx_kernel(
    const unsigned short* __restrict__ Qb, const unsigned short* __restrict__ Kb,
    const unsigned short* __restrict__ Vt, const float* __restrict__ invzG,
    unsigned short* __restrict__ ctx)
{
  __shared__ unsigned short Pld[64][76];
  const int tid = threadIdx.x;
  const int lane = tid & 63, wave = tid >> 6;
  const int c = lane & 15, quad = lane >> 4;
  const int qt = blockIdx.x & 15;
  const int h  = (blockIdx.x >> 4) & 7;
  const int b  = blockIdx.x >> 7;
  const size_t bT = (size_t)b * Tz;
  const int qrow = qt * 64 + wave * 16;
  const int hoff = h * DHz;

  const size_t qbase = (bT + qrow + c) * Dz + hoff + quad * 8;
  short8 q0 = *reinterpret_cast<const short8*>(Qb + qbase);
  short8 q1 = *reinterpret_cast<const short8*>(Qb + qbase + 32);

  float invz[4];
#pragma unroll
  for (int rr = 0; rr < 4; ++rr)
    invz[rr] = invzG[(size_t)(b * Hz + h) * Tz + qrow + quad * 4 + rr];

  const f32x4 zf = {0.f, 0.f, 0.f, 0.f};
  f32x4 ot[4] = {zf, zf, zf, zf};

  for (int t = 0; t < 16; ++t) {
    const int k0 = t * 64;
#pragma unroll
    for (int sub = 0; sub < 4; ++sub) {
      const size_t kb = (bT + k0 + sub * 16 + c) * Dz + hoff + quad * 8;
      short8 kh0 = *reinterpret_cast<const short8*>(Kb + kb);
      short8 kh1 = *reinterpret_cast<const short8*>(Kb + kb + 32);
      f32x4 acc = zf;
      acc = __builtin_amdgcn_mfma_f32_16x16x32_bf16(q0, kh0, acc, 0, 0, 0);
      acc = __builtin_amdgcn_mfma_f32_16x16x32_bf16(q1, kh1, acc, 0, 0, 0);
#pragma unroll
      for (int rr = 0; rr < 4; ++rr) {
        float p = __expf(acc[rr] * 0.125f) * invz[rr];
        Pld[(wave << 4) + quad * 4 + rr][sub * 16 + c] = f2bf(p);
      }
    }
    union { short8 v; ushort4 hh[2]; } pb0, pb1;
    pb0.hh[0] = *reinterpret_cast<const ushort4*>(&Pld[(wave << 4) + c][quad * 8]);
    pb0.hh[1] = *reinterpret_cast<const ushort4*>(&Pld[(wave << 4) + c][quad * 8 + 4]);
    pb1.hh[0] = *reinterpret_cast<const ushort4*>(&Pld[(wave << 4) + c][32 + quad * 8]);
    pb1.hh[1] = *reinterpret_cast<const ushort4*>(&Pld[(wave << 4) + c][32 + quad * 8 + 4]);
#pragma unroll
    for (int ds = 0; ds < 4; ++ds) {
      const size_t va = ((size_t)((b * Hz + h) * DHz + ds * 16 + c)) * Tz + k0 + quad * 8;
      short8 v0 = *reinterpret_cast<const short8*>(Vt + va);
      short8 v1 = *reinterpret_cast<const short8*>(Vt + va + 32);
      ot[ds] = __builtin_amdgcn_mfma_f32_16x16x32_bf16(v0, pb0.v, ot[ds], 0, 0, 0);
      ot[ds] = __builtin_amdgcn_mfma_f32_16x16x32_bf16(v1, pb1.v, ot[ds], 0, 0, 0);
    }
  }

  const size_t cb = (bT + qrow + c) * Dz + hoff;
#pragma unroll
  for (int ds = 0; ds < 4; ++ds) {
    ushort4 pk;
    pk.x = f2bf(ot[ds][0]); pk.y = f2bf(ot[ds][1]);
    pk.z = f2bf(ot[ds][2]); pk.w = f2bf(ot[ds][3]);
    *reinterpret_cast<ushort4*>(&ctx[cb + ds * 16 + quad * 4]) = pk;
  }
}

// ---------------------------------------------------------------------------
// Layer-2 MFMA attention (masked), with k-tile range skipping. CS2 feeds only
// the continuous wl softmax -> atomics are fine here.
// ---------------------------------------------------------------------------
__global__ __launch_bounds__(256) void attn_mfma2_kernel(
    const unsigned short* __restrict__ Qh, const unsigned short* __restrict__ Kh,
    const unsigned short* __restrict__ Vt, const int* __restrict__ ids,
    const int* __restrict__ wst,
    unsigned short* __restrict__ ctx, float* __restrict__ colsum)
{
  __shared__ unsigned short Pld[64][76];
  __shared__ float csb[1024];

  const int tid = threadIdx.x;
  const int lane = tid & 63, wave = tid >> 6;
  const int c = lane & 15, quad = lane >> 4;
  const int qt = blockIdx.x & 15;
  const int h  = (blockIdx.x >> 4) & 7;
  const int b  = blockIdx.x >> 7;
  const size_t bT = (size_t)b * Tz;
  const int qrow = qt * 64 + wave * 16;
  const int hoff = h * DHz;

  for (int i = tid; i < 1024; i += 256) csb[i] = 0.f;

  const int id_lo = ids[bT + qt * 64];
  const int id_hi = ids[bT + qt * 64 + 63];
  const int klo = wst[b * (Tz + 1) + id_lo];
  const int khi = wst[b * (Tz + 1) + id_hi + 1];
  const int t0 = klo >> 6, t1 = (khi - 1) >> 6;

  const size_t qbase = (bT + qrow + c) * Dz + hoff + quad * 8;
  short8 q0 = *reinterpret_cast<const short8*>(Qh + qbase);
  short8 q1 = *reinterpret_cast<const short8*>(Qh + qbase + 32);

  int qid[4];
#pragma unroll
  for (int rr = 0; rr < 4; ++rr) qid[rr] = ids[bT + qrow + quad * 4 + rr];
  __syncthreads();  // csb zeros visible before pass-2 atomics

  const f32x4 zf = {0.f, 0.f, 0.f, 0.f};

  // pass 1: z
  float z[4] = {0.f, 0.f, 0.f, 0.f};
  for (int t = t0; t <= t1; ++t) {
    const int k0 = t * 64;
#pragma unroll
    for (int sub = 0; sub < 4; ++sub) {
      const size_t kb = (bT + k0 + sub * 16 + c) * Dz + hoff + quad * 8;
      short8 kh0 = *reinterpret_cast<const short8*>(Kh + kb);
      short8 kh1 = *reinterpret_cast<const short8*>(Kh + kb + 32);
      f32x4 acc = zf;
      acc = __builtin_amdgcn_mfma_f32_16x16x32_bf16(q0, kh0, acc, 0, 0, 0);
      acc = __builtin_amdgcn_mfma_f32_16x16x32_bf16(q1, kh1, acc, 0, 0, 0);
      int kidv = ids[bT + k0 + sub * 16 + c];
#pragma unroll
      for (int rr = 0; rr < 4; ++rr) {
        float e = __expf(acc[rr] * 0.125f);
        if (qid[rr] != kidv) e = 0.f;
        z[rr] += e;
      }
    }
  }
#pragma unroll
  for (int w = 1; w < 16; w <<= 1) {
#pragma unroll
    for (int rr = 0; rr < 4; ++rr) z[rr] += __shfl_xor(z[rr], w);
  }
  float invz[4];
#pragma unroll
  for (int rr = 0; rr < 4; ++rr) invz[rr] = 1.f / z[rr];

  // pass 2: P, colsum, PV
  f32x4 ot[4] = {zf, zf, zf, zf};
  for (int t = t0; t <= t1; ++t) {
    const int k0 = t * 64;
#pragma unroll
    for (int sub = 0; sub < 4; ++sub) {
      const size_t kb = (bT + k0 + sub * 16 + c) * Dz + hoff + quad * 8;
      short8 kh0 = *reinterpret_cast<const short8*>(Kh + kb);
      short8 kh1 = *reinterpret_cast<const short8*>(Kh + kb + 32);
      f32x4 acc = zf;
      acc = __builtin_amdgcn_mfma_f32_16x16x32_bf16(q0, kh0, acc, 0, 0, 0);
      acc = __builtin_amdgcn_mfma_f32_16x16x32_bf16(q1, kh1, acc, 0, 0, 0);
      int kidv = ids[bT + k0 + sub * 16 + c];
      float p[4];
#pragma unroll
      for (int rr = 0; rr < 4; ++rr) {
        float e = __expf(acc[rr] * 0.125f);
        if (qid[rr] != kidv) e = 0.f;
        p[rr] = e * invz[rr];
      }
      float cs = p[0] + p[1] + p[2] + p[3];
      cs += __shfl_xor(cs, 16);
      cs += __shfl_xor(cs, 32);
      if (quad == 0) atomicAdd(&csb[k0 + sub * 16 + c], cs);
#pragma unroll
      for (int rr = 0; rr < 4; ++rr)
        Pld[(wave << 4) + quad * 4 + rr][sub * 16 + c] = f2bf(p[rr]);
    }
    union { short8 v; ushort4 hh[2]; } pb0, pb1;
    pb0.hh[0] = *reinterpret_cast<const ushort4*>(&Pld[(wave << 4) + c][quad * 8]);
    pb0.hh[1] = *reinterpret_cast<const ushort4*>(&Pld[(wave << 4) + c][quad * 8 + 4]);
    pb1.hh[0] = *reinterpret_cast<const ushort4*>(&Pld[(wave << 4) + c][32 + quad * 8]);
    pb1.hh[1] = *reinterpret_cast<const ushort4*>(&Pld[(wave << 4) + c][32 + quad * 8 + 4]);
#pragma unroll
    for (int ds = 0; ds < 4; ++ds) {
      const size_t va = ((size_t)((b * Hz + h) * DHz + ds * 16 + c)) * Tz + k0 + quad * 8;
      short8 v0 = *reinterpret_cast<const short8*>(Vt + va);
      short8 v1 = *reinterpret_cast<const short8*>(Vt + va + 32);
      ot[ds] = __builtin_amdgcn_mfma_f32_16x16x32_bf16(v0, pb0.v, ot[ds], 0, 0, 0);
      ot[ds] = __builtin_amdgcn_mfma_f32_16x16x32_bf16(v1, pb1.v, ot[ds], 0, 0, 0);
    }
  }

  const size_t cb = (bT + qrow + c) * Dz + hoff;
#pragma unroll
  for (int ds = 0; ds < 4; ++ds) {
    ushort4 pk;
    pk.x = f2bf(ot[ds][0]); pk.y = f2bf(ot[ds][1]);
    pk.z = f2bf(ot[ds][2]); pk.w = f2bf(ot[ds][3]);
    *reinterpret_cast<ushort4*>(&ctx[cb + ds * 16 + quad * 4]) = pk;
  }
  __syncthreads();
  for (int i = tid; i < 1024; i += 256)
    atomicAdd(&colsum[bT + i], csb[i] * (1.f / Hz));
}

// ---------------------------------------------------------------------------
// out = LayerNorm(resid + delta). resid fp32 (residf) if non-null else bf16.
// ---------------------------------------------------------------------------
__global__ __launch_bounds__(256) void ln_kernel(const float* __restrict__ residf,
    const unsigned short* __restrict__ residbf, const float* __restrict__ delta,
    float* __restrict__ outf, unsigned short* __restrict__ outbf)
{
  const size_t base = (size_t)blockIdx.x * Dz;
  const int tid = threadIdx.x;
  float r0, r1;
  if (residf) {
    r0 = residf[base + tid]; r1 = residf[base + tid + 256];
  } else {
    r0 = bf2f(residbf[base + tid]); r1 = bf2f(residbf[base + tid + 256]);
  }
  float x0 = r0 + delta[base + tid];
  float x1 = r1 + delta[base + tid + 256];
  __shared__ float red[4];
  float s = x0 + x1;
#pragma unroll
  for (int off = 32; off; off >>= 1) s += __shfl_down(s, off);
  if ((tid & 63) == 0) red[tid >> 6] = s;
  __syncthreads();
  const float mean = (red[0] + red[1] + red[2] + red[3]) * (1.f / Dz);
  __syncthreads();
  float d0 = x0 - mean, d1 = x1 - mean;
  float v = d0 * d0 + d1 * d1;
#pragma unroll
  for (int off = 32; off; off >>= 1) v += __shfl_down(v, off);
  if ((tid & 63) == 0) red[tid >> 6] = v;
  __syncthreads();
  const float var = (red[0] + red[1] + red[2] + red[3]) * (1.f / Dz);
  const float rstd = rsqrtf(var + 1e-5f);
  float y0 = d0 * rstd, y1 = d1 * rstd;
  if (outf) {
    outf[base + tid] = y0;
    outf[base + tid + 256] = y1;
  }
  outbf[base + tid] = f2bf(y0);
  outbf[base + tid + 256] = f2bf(y1);
}

// ---------------------------------------------------------------------------
// Per batch: min-max normalize colsum, threshold 0.5, run-length window scan.
// All reductions shfl/fixed-order -> deterministic.
// ---------------------------------------------------------------------------
__global__ __launch_bounds__(256) void window_ids_kernel(const float* __restrict__ cs,
    int* __restrict__ ids, int* __restrict__ wst, int* __restrict__ nwin)
{
  const int b = blockIdx.x, tid = threadIdx.x;
  __shared__ float vals[Tz];
  __shared__ unsigned char wb[Tz];
  __shared__ int sids[Tz];
  __shared__ float rmin[4], rmax[4];
  float mn = INFINITY, mx = -INFINITY;
  for (int t = tid; t < Tz; t += 256) {
    float v = cs[b * Tz + t];
    vals[t] = v;
    mn = fminf(mn, v); mx = fmaxf(mx, v);
  }
#pragma unroll
  for (int off = 32; off; off >>= 1) {
    mn = fminf(mn, __shfl_down(mn, off));
    mx = fmaxf(mx, __shfl_down(mx, off));
  }
  if ((tid & 63) == 0) { rmin[tid >> 6] = mn; rmax[tid >> 6] = mx; }
  __syncthreads();
  mn = fminf(fminf(rmin[0], rmin[1]), fminf(rmin[2], rmin[3]));
  mx = fmaxf(fmaxf(rmax[0], rmax[1]), fmaxf(rmax[2], rmax[3]));
  const float inv = 1.f / (mx - mn + 1e-8f);
  for (int t = tid; t < Tz; t += 256) wb[t] = (((vals[t] - mn) * inv) >= 0.5f) ? 1 : 0;
  __syncthreads();
  if (tid == 0) {
    int cur = wb[0], start = 0, wid = 0;
    sids[0] = 0;
    wst[b * (Tz + 1)] = 0;
    for (int t = 1; t < Tz; ++t) {
      int wt = wb[t];
      if (wt != cur) {
        cur = wt;
        if (start + 1 != t) {
          start = t;
          ++wid;
          wst[b * (Tz + 1) + wid] = t;
        }
      }
      sids[t] = wid;
    }
    nwin[b] = wid + 1;
    wst[b * (Tz + 1) + wid + 1] = Tz;
  }
  __syncthreads();
  for (int t = tid; t < Tz; t += 256) ids[b * Tz + t] = sids[t];
}

// ---------------------------------------------------------------------------
// wl[b,:] = softmax over keys of layer-2 colsum.
// ---------------------------------------------------------------------------
__global__ __launch_bounds__(256) void wl_softmax_kernel(const float* __restrict__ cs,
                                                         float* __restrict__ wl)
{
  const int b = blockIdx.x, tid = threadIdx.x;
  __shared__ float vals[Tz];
  __shared__ float red[4];
  float mx = -INFINITY;
  for (int t = tid; t < Tz; t += 256) {
    float v = cs[b * Tz + t];
    vals[t] = v;
    mx = fmaxf(mx, v);
  }
#pragma unroll
  for (int off = 32; off; off >>= 1) mx = fmaxf(mx, __shfl_down(mx, off));
  if ((tid & 63) == 0) red[tid >> 6] = mx;
  __syncthreads();
  mx = fmaxf(fmaxf(red[0], red[1]), fmaxf(red[2], red[3]));
  __syncthreads();
  float se = 0.f;
  for (int t = tid; t < Tz; t += 256) {
    float e = expf(vals[t] - mx);
    vals[t] = e;
    se += e;
  }
#pragma unroll
  for (int off = 32; off; off >>= 1) se += __shfl_down(se, off);
  if ((tid & 63) == 0) red[tid >> 6] = se;
  __syncthreads();
  const float inv = 1.f / (red[0] + red[1] + red[2] + red[3]);
  for (int t = tid; t < Tz; t += 256) wl[b * Tz + t] = vals[t] * inv;
}

// ---------------------------------------------------------------------------
// Fused outputs: word_tokens (blocks 0..8191), winmap (8192..16383),
// copy_x (16384..20479).
// ---------------------------------------------------------------------------
__global__ __launch_bounds__(256) void outputs_kernel(
    const unsigned short* __restrict__ outl, const float* __restrict__ wl,
    const int* __restrict__ wst, const int* __restrict__ nwin,
    const int* __restrict__ ids, const float* __restrict__ x,
    float* __restrict__ out, float* __restrict__ out2)
{
  const int bid = blockIdx.x;
  const int tid = threadIdx.x;
  if (bid < 8192) {  // word_tokens
    const int w = bid & (Tz - 1);
    const int b = bid >> 10;
    float a0 = 0.f, a1 = 0.f;
    if (w < nwin[b]) {
      const int s = wst[b * (Tz + 1) + w], e = wst[b * (Tz + 1) + w + 1];
      for (int t = s; t < e; ++t) {
        const float sc = wl[b * Tz + t];
        const unsigned short* p = &outl[((size_t)(b * Tz + t)) * Dz];
        a0 += bf2f(p[tid]) * sc;
        a1 += bf2f(p[tid + 256]) * sc;
      }
    }
    float* o = &out[((size_t)(b * 2 * Tz + w)) * Dz];
    o[tid] = a0;
    o[tid + 256] = a1;
  } else if (bid < 16384) {  // winmap
    const int lb = bid - 8192;
    const int w = lb & (Tz - 1);
    const int b = lb >> 10;
    const int j = tid * 4;
    int4 id4 = *reinterpret_cast<const int4*>(&ids[b * Tz + j]);
    float4 v;
    v.x = (id4.x == w) ? 1.f : 0.f;
    v.y = (id4.y == w) ? 1.f : 0.f;
    v.z = (id4.z == w) ? 1.f : 0.f;
    v.w = (id4.w == w) ? 1.f : 0.f;
    *reinterpret_cast<float4*>(&out2[((size_t)(b * Tz + w)) * Tz + j]) = v;
  } else {  // copy_x
    size_t i = (size_t)(bid - 16384) * 256 + tid;
    size_t idx = i * 4;
    size_t rowi = idx >> 9;
    size_t d = idx & 511;
    size_t b = rowi >> 10, t = rowi & 1023;
    float4 v = *reinterpret_cast<const float4*>(&x[idx]);
    *reinterpret_cast<float4*>(&out[(((b * 2 * Tz) + Tz + t) << 9) + d]) = v;
  }
}

// ---------------------------------------------------------------------------
// Orchestration: 22 dispatches. PART aliases the dead-XBF region (V^T GEMM
// moved before colsum to free it).
// ---------------------------------------------------------------------------
extern "C" void kernel_launch(void* const* d_in, const int* in_sizes, int n_in,
                              void* d_out, int out_size, void* d_ws, size_t ws_size,
                              hipStream_t stream)
{
  (void)in_sizes; (void)n_in; (void)out_size; (void)ws_size;
  const float* x     = (const float*)d_in[0];
  const float* vqkv  = (const float*)d_in[1];
  const float* voutw = (const float*)d_in[2];
  const float* vw1   = (const float*)d_in[3];
  const float* vw2   = (const float*)d_in[4];
  const float* lqkv  = (const float*)d_in[5];
  const float* loutw = (const float*)d_in[6];
  const float* lw1   = (const float*)d_in[7];
  const float* lw2   = (const float*)d_in[8];
  float* out = (float*)d_out;
  float* ws  = (float*)d_ws;

  float* Qf = ws + 0;           // fp32 Q (L1), dead after colsum -> PROJ
  float* Kf = ws + 4194304;     // fp32 K (L1), dead after colsum -> Y1
  float* PROJ = ws + 0;         // alias Qf
  float* Y1   = ws + 4194304;   // alias Kf
  unsigned short* QHbf = (unsigned short*)(ws + 8388608);   // bf16 Q (L1+L2)
  unsigned short* KHbf = (unsigned short*)(ws + 10485760);  // bf16 K (L1+L2)
  unsigned short* VT   = (unsigned short*)(ws + 12582912);
  unsigned short* SLOT1 = (unsigned short*)(ws + 14680064); // attn ctx bf16
  unsigned short* SLOT2 = (unsigned short*)(ws + 16777216); // LN bf16 out
  unsigned short* HIDbf = (unsigned short*)(ws + 18874368); // FFN hidden
  unsigned short* XBF   = (unsigned short*)(ws + 18874368); // alias (pre-FFN)
  float* PART = ws + 18874368;  // colsum block partials (1024x1024), alias:
                                // written after XBF is dead, dead before FFN1
  // bf16 transposed weights (WLQ0..2 contiguous -> merged [1536,512] matrix)
  unsigned short* WVQV = (unsigned short*)(ws + 27262976);
  unsigned short* WVO  = (unsigned short*)(ws + 27394048);
  unsigned short* WV1  = (unsigned short*)(ws + 27525120);
  unsigned short* WV2  = (unsigned short*)(ws + 28049408);
  unsigned short* WLQ0 = (unsigned short*)(ws + 28573696);
  unsigned short* WLQ1 = (unsigned short*)(ws + 28704768);
  unsigned short* WLQ2 = (unsigned short*)(ws + 28835840);
  unsigned short* WLO  = (unsigned short*)(ws + 28966912);
  unsigned short* WL1  = (unsigned short*)(ws + 29097984);
  unsigned short* WL2  = (unsigned short*)(ws + 29622272);
  // small buffers
  float* CS1   = ws + 30146560;
  float* CS2   = ws + 30154752;
  float* WLs   = ws + 30162944;
  int*   IDS   = (int*)(ws + 30171136);
  int*   WST   = (int*)(ws + 30179328);
  int*   NWIN  = (int*)(ws + 30187776);
  float* INVZ  = ws + 30195968;  // (B*H*T) = 65536 floats

  dim3 blk(256);

  // ---- fused prep: 10 wconv + zero + fconv ----
  PrepArgs P;
  auto setw = [&](int i, const float* s, unsigned short* d, int K, int N, int b0) {
    P.d[i].src = s; P.d[i].dst = d; P.d[i].K = K; P.d[i].N = N; P.d[i].blk0 = b0;
  };
  int b0 = 0;
  setw(0, vqkv + 2 * Dz * Dz, WVQV, Dz, Dz, b0); b0 += 256;
  setw(1, voutw, WVO, Dz, Dz, b0); b0 += 256;
  setw(2, vw1, WV1, Dz, FFz, b0); b0 += 1024;
  setw(3, vw2, WV2, FFz, Dz, b0); b0 += 1024;
  setw(4, lqkv + 0 * Dz * Dz, WLQ0, Dz, Dz, b0); b0 += 256;
  setw(5, lqkv + 1 * Dz * Dz, WLQ1, Dz, Dz, b0); b0 += 256;
  setw(6, lqkv + 2 * Dz * Dz, WLQ2, Dz, Dz, b0); b0 += 256;
  setw(7, loutw, WLO, Dz, Dz, b0); b0 += 256;
  setw(8, lw1, WL1, Dz, FFz, b0); b0 += 1024;
  setw(9, lw2, WL2, FFz, Dz, b0); b0 += 1024;
  P.nwc = b0;  // 5632
  prep_kernel<<<dim3(P.nwc + 64 + 4096), blk, 0, stream>>>(P, x, XBF, CS1);

  auto mgemm = [&](const unsigned short* A, const unsigned short* BT, void* p1,
                   void* p2, void* p3, int K, int N, int mode) {
    mfma_gemm_kernel<<<dim3(N / 64, Mz / 64), dim3(64), 0, stream>>>(
        A, BT, p1, p2, p3, K, N, mode);
  };

  // ---------------- layer 1 (vanilla) ----------------
  gemm_qk_kernel<<<dim3(4, 128), blk, 0, stream>>>(x, vqkv, Qf, QHbf, Kf, KHbf, Dz, Dz);
  mgemm(XBF, WVQV, VT, nullptr, nullptr, Dz, Dz, 4);        // V -> V^T (XBF dead after)
  colsum_f32_kernel<<<dim3(Bz * Hz * 16), blk, 0, stream>>>(Qf, Kf, PART, INVZ);
  colsum_reduce_kernel<<<dim3(32), blk, 0, stream>>>(PART, CS1);
  window_ids_kernel<<<dim3(Bz), blk, 0, stream>>>(CS1, IDS, WST, NWIN);
  attn_ctx_kernel<<<dim3(Bz * Hz * 16), blk, 0, stream>>>(QHbf, KHbf, VT, INVZ, SLOT1);
  mgemm(SLOT1, WVO, PROJ, nullptr, nullptr, Dz, Dz, 0);     // proj (Qf dead)
  ln_kernel<<<dim3(Mz), blk, 0, stream>>>(x, nullptr, PROJ, Y1, SLOT2);
  mgemm(SLOT2, WV1, HIDbf, nullptr, nullptr, Dz, FFz, 2);   // FFN1 + ReLU (PART dead)
  mgemm(HIDbf, WV2, PROJ, nullptr, nullptr, FFz, Dz, 0);    // FFN2
  ln_kernel<<<dim3(Mz), blk, 0, stream>>>(Y1, nullptr, PROJ, nullptr, SLOT2);

  // ---------------- layer 2 (block-diagonal window mask) ----------------
  mgemm(SLOT2, WLQ0, QHbf, KHbf, VT, Dz, 3 * Dz, 5);        // merged QKV
  attn_mfma2_kernel<<<dim3(Bz * Hz * 16), blk, 0, stream>>>(
      QHbf, KHbf, VT, IDS, WST, SLOT1, CS2);
  mgemm(SLOT1, WLO, PROJ, nullptr, nullptr, Dz, Dz, 0);
  ln_kernel<<<dim3(Mz), blk, 0, stream>>>(nullptr, SLOT2, PROJ, Y1, SLOT2);
  mgemm(SLOT2, WL1, HIDbf, nullptr, nullptr, Dz, FFz, 2);
  mgemm(HIDbf, WL2, PROJ, nullptr, nullptr, FFz, Dz, 0);
  ln_kernel<<<dim3(Mz), blk, 0, stream>>>(Y1, nullptr, PROJ, nullptr, SLOT2);

  // ---------------- pooling + outputs ----------------
  wl_softmax_kernel<<<dim3(Bz), blk, 0, stream>>>(CS2, WLs);
  outputs_kernel<<<dim3(20480), blk, 0, stream>>>(SLOT2, WLs, WST, NWIN, IDS, x,
                                                  out, out + (size_t)Bz * 2 * Tz * Dz);
}